// Round 1
// baseline (671.312 us; speedup 1.0000x reference)
//
#include <hip/hip_runtime.h>

#define B_ 2
#define S_ 2048
#define D_ 2048
#define NH 16
#define NKV 8
#define HD 128
#define SCALE 0.08838834764831845f

typedef unsigned short u16;
typedef __attribute__((ext_vector_type(8))) short short8;
typedef __attribute__((ext_vector_type(4))) float f32x4;

__device__ __forceinline__ u16 f2b(float f) {
  union { float f; unsigned u; } c; c.f = f;
  unsigned u = c.u;
  return (u16)((u + 0x7fffu + ((u >> 16) & 1u)) >> 16);
}
__device__ __forceinline__ float b2f(u16 h) {
  union { unsigned u; float f; } c; c.u = ((unsigned)h) << 16;
  return c.f;
}

__device__ __forceinline__ void load_lds16(const u16* g, u16* l) {
  __builtin_amdgcn_global_load_lds(
      (const __attribute__((address_space(1))) unsigned int*)g,
      (__attribute__((address_space(3))) unsigned int*)l, 16, 0, 0);
}

// ---------------- f32 -> bf16 conversion ----------------
__global__ __launch_bounds__(256) void cvt_f32_bf16(const float* __restrict__ src,
                                                    u16* __restrict__ dst, int n4) {
  int i = blockIdx.x * 256 + threadIdx.x;
  if (i >= n4) return;
  float4 v = ((const float4*)src)[i];
  u16 o0 = f2b(v.x), o1 = f2b(v.y), o2 = f2b(v.z), o3 = f2b(v.w);
  unsigned long long packed = (unsigned long long)o0 | ((unsigned long long)o1 << 16) |
                              ((unsigned long long)o2 << 32) | ((unsigned long long)o3 << 48);
  ((unsigned long long*)dst)[i] = packed;
}

// ---------------- GEMM: C[M,N] = A[M,K] * B[N,K]^T (bf16 in, f32 acc) ----------------
// 128x128 tile, BK=64, 4 waves (2x2), XOR-swizzled LDS, global_load_lds staging.
template<int OUTF32>
__global__ __launch_bounds__(256) void gemm_bt(const u16* __restrict__ A, const u16* __restrict__ Bm,
                                               void* __restrict__ Cv, int M, int N, int K) {
  __shared__ __align__(16) u16 As[128 * 64];
  __shared__ __align__(16) u16 Bs[128 * 64];
  const int tid = threadIdx.x;
  const int wave = tid >> 6, lane = tid & 63;
  const int bm = blockIdx.x, bn = blockIdx.y;
  const int wr = wave >> 1, wc = wave & 1;
  const int r = lane & 15, hi = lane >> 4;

  f32x4 acc[4][4];
#pragma unroll
  for (int m = 0; m < 4; ++m)
#pragma unroll
    for (int n = 0; n < 4; ++n) acc[m][n] = (f32x4){0.f, 0.f, 0.f, 0.f};

  const int gslot = (lane & 7) ^ (lane >> 3);  // swizzled global col-group for staging
  const int srow_in_chunk = lane >> 3;

  for (int k0 = 0; k0 < K; k0 += 64) {
#pragma unroll
    for (int jj = 0; jj < 4; ++jj) {
      int j = wave * 4 + jj;
      int row = j * 8 + srow_in_chunk;
      const u16* ga = A + (size_t)(bm * 128 + row) * K + k0 + gslot * 8;
      load_lds16(ga, &As[j * 512]);
      const u16* gb = Bm + (size_t)(bn * 128 + row) * K + k0 + gslot * 8;
      load_lds16(gb, &Bs[j * 512]);
    }
    __syncthreads();
#pragma unroll
    for (int kc = 0; kc < 2; ++kc) {
      short8 af[4], bfr[4];
#pragma unroll
      for (int m = 0; m < 4; ++m) {
        int row = wr * 64 + m * 16 + r;
        int slot = (hi + kc * 4) ^ (row & 7);
        af[m] = *(const short8*)&As[row * 64 + slot * 8];
      }
#pragma unroll
      for (int n = 0; n < 4; ++n) {
        int row = wc * 64 + n * 16 + r;
        int slot = (hi + kc * 4) ^ (row & 7);
        bfr[n] = *(const short8*)&Bs[row * 64 + slot * 8];
      }
#pragma unroll
      for (int m = 0; m < 4; ++m)
#pragma unroll
        for (int n = 0; n < 4; ++n)
          acc[m][n] = __builtin_amdgcn_mfma_f32_16x16x32_bf16(af[m], bfr[n], acc[m][n], 0, 0, 0);
    }
    __syncthreads();
  }

  // epilogue: C/D layout col=lane&15, row=(lane>>4)*4+reg
#pragma unroll
  for (int m = 0; m < 4; ++m)
#pragma unroll
    for (int n = 0; n < 4; ++n)
#pragma unroll
      for (int r2 = 0; r2 < 4; ++r2) {
        int grow = bm * 128 + wr * 64 + m * 16 + hi * 4 + r2;
        int gcol = bn * 128 + wc * 64 + n * 16 + r;
        if (OUTF32)
          ((float*)Cv)[(size_t)grow * N + gcol] = acc[m][n][r2];
        else
          ((u16*)Cv)[(size_t)grow * N + gcol] = f2b(acc[m][n][r2]);
      }
}

// ---------------- per-head RMSNorm + RoPE for Q and K ----------------
// one wave per (token, head-row); qkv row layout: [q 2048 | k 1024 | v 1024]
__global__ __launch_bounds__(256) void rmsnorm_rope(const u16* __restrict__ qkv, const float* __restrict__ fc,
                                                    const float* __restrict__ qw, const float* __restrict__ kw,
                                                    u16* __restrict__ qr, u16* __restrict__ kr) {
  const int tid = threadIdx.x, wave = tid >> 6, lane = tid & 63;
  const int rowid = blockIdx.x * 4 + wave;  // 0 .. 98303
  const int token = rowid / 24;
  const int hh = rowid % 24;
  const int b = token >> 11, s = token & 2047;
  const bool isq = hh < 16;
  const int off = isq ? hh * 128 : 2048 + (hh - 16) * 128;
  const u16* src = qkv + (size_t)token * 4096 + off + lane * 2;
  unsigned pv = *(const unsigned*)src;
  float t0 = b2f((u16)(pv & 0xffffu));
  float t1 = b2f((u16)(pv >> 16));
  float ss = t0 * t0 + t1 * t1;
#pragma unroll
  for (int mm = 1; mm < 64; mm <<= 1) ss += __shfl_xor(ss, mm, 64);
  float rms = rsqrtf(ss * (1.0f / 128.0f) + 1e-6f);
  const float* nw = isq ? qw : kw;
  t0 *= rms * nw[lane * 2];
  t1 *= rms * nw[lane * 2 + 1];
  float c = fc[(s * 64 + lane) * 2], sn = fc[(s * 64 + lane) * 2 + 1];
  float o0 = t0 * c - t1 * sn;
  float o1 = t0 * sn + t1 * c;
  unsigned ov = (unsigned)f2b(o0) | ((unsigned)f2b(o1) << 16);
  if (isq)
    *(unsigned*)(qr + ((size_t)(b * 16 + hh) * 2048 + s) * 128 + lane * 2) = ov;
  else
    *(unsigned*)(kr + ((size_t)(b * 8 + hh - 16) * 2048 + s) * 128 + lane * 2) = ov;
}

// ---------------- V transpose: qkv v-section -> vt[b][hkv][d][s] ----------------
__global__ __launch_bounds__(256) void v_transpose(const u16* __restrict__ qkv, u16* __restrict__ vt) {
  __shared__ __align__(16) u16 tile[64][136];
  const int blk = blockIdx.x;
  const int st = blk & 31, h = (blk >> 5) & 7, b = blk >> 8;
  const int s0 = st * 64, t = threadIdx.x;
#pragma unroll
  for (int p = 0; p < 4; ++p) {
    int row = p * 16 + (t >> 4), c8 = (t & 15) * 8;
    const u16* src = qkv + (size_t)(b * 2048 + s0 + row) * 4096 + 3072 + h * 128 + c8;
    *(short8*)&tile[row][c8] = *(const short8*)src;
  }
  __syncthreads();
  const int d = t >> 1, j0 = (t & 1) * 32;
  u16* dst = vt + ((size_t)(b * 8 + h) * 128 + d) * 2048 + s0 + j0;
#pragma unroll
  for (int j = 0; j < 32; j += 8) {
    short8 v;
#pragma unroll
    for (int u = 0; u < 8; ++u) v[u] = (short)tile[j0 + j + u][d];
    *(short8*)(dst + j) = v;
  }
}

// ---------------- causal flash attention ----------------
// block: 4 waves; each wave owns a 16-row q tile of one (b,h). KBLK=32.
__global__ __launch_bounds__(256) void attn(const u16* __restrict__ qr, const u16* __restrict__ kr,
                                            const u16* __restrict__ vt, u16* __restrict__ ao) {
  __shared__ __align__(16) u16 plds[4][16][40];
  const int tid = threadIdx.x, wave = tid >> 6, lane = tid & 63;
  const int blk = blockIdx.x;
  const int qt = blk & 31, h = (blk >> 5) & 15, b = blk >> 9;
  const int q0 = qt * 64 + wave * 16;
  const int hkv = h >> 1;
  const u16* Q = qr + (size_t)(b * 16 + h) * S_ * HD;
  const u16* Kp = kr + (size_t)(b * 8 + hkv) * S_ * HD;
  const u16* Vt = vt + (size_t)(b * 8 + hkv) * HD * S_;
  const int r = lane & 15, hi = lane >> 4;

  short8 qf[4];
#pragma unroll
  for (int c = 0; c < 4; ++c)
    qf[c] = *(const short8*)(Q + (size_t)(q0 + r) * HD + c * 32 + hi * 8);

  f32x4 o[8];
#pragma unroll
  for (int n = 0; n < 8; ++n) o[n] = (f32x4){0.f, 0.f, 0.f, 0.f};
  float mrow[4] = {-1e30f, -1e30f, -1e30f, -1e30f};
  float lrow[4] = {0.f, 0.f, 0.f, 0.f};

  const int kvend = q0 + 16;
  for (int kv0 = 0; kv0 < kvend; kv0 += 32) {
    f32x4 sacc0 = (f32x4){0.f, 0.f, 0.f, 0.f};
    f32x4 sacc1 = sacc0;
#pragma unroll
    for (int c = 0; c < 4; ++c) {
      short8 kf0 = *(const short8*)(Kp + (size_t)(kv0 + r) * HD + c * 32 + hi * 8);
      sacc0 = __builtin_amdgcn_mfma_f32_16x16x32_bf16(qf[c], kf0, sacc0, 0, 0, 0);
      short8 kf1 = *(const short8*)(Kp + (size_t)(kv0 + 16 + r) * HD + c * 32 + hi * 8);
      sacc1 = __builtin_amdgcn_mfma_f32_16x16x32_bf16(qf[c], kf1, sacc1, 0, 0, 0);
    }
    const int c0 = kv0 + r, c1 = kv0 + 16 + r;
#pragma unroll
    for (int rr = 0; rr < 4; ++rr) {
      int qrow = q0 + hi * 4 + rr;
      float s0v = (c0 <= qrow) ? sacc0[rr] * SCALE : -1e30f;
      float s1v = (c1 <= qrow) ? sacc1[rr] * SCALE : -1e30f;
      float mx = fmaxf(s0v, s1v);
#pragma unroll
      for (int mm = 1; mm < 16; mm <<= 1) mx = fmaxf(mx, __shfl_xor(mx, mm, 64));
      float mnew = fmaxf(mrow[rr], mx);
      float p0 = __expf(s0v - mnew);
      float p1 = __expf(s1v - mnew);
      float rs = p0 + p1;
#pragma unroll
      for (int mm = 1; mm < 16; mm <<= 1) rs += __shfl_xor(rs, mm, 64);
      float sc = __expf(mrow[rr] - mnew);
      lrow[rr] = lrow[rr] * sc + rs;
      mrow[rr] = mnew;
#pragma unroll
      for (int n = 0; n < 8; ++n) o[n][rr] *= sc;
      plds[wave][hi * 4 + rr][r] = f2b(p0);
      plds[wave][hi * 4 + rr][16 + r] = f2b(p1);
    }
    asm volatile("s_waitcnt lgkmcnt(0)" ::: "memory");
    short8 pf = *(const short8*)&plds[wave][r][hi * 8];
#pragma unroll
    for (int n = 0; n < 8; ++n) {
      short8 vf = *(const short8*)(Vt + (size_t)(n * 16 + r) * S_ + kv0 + hi * 8);
      o[n] = __builtin_amdgcn_mfma_f32_16x16x32_bf16(pf, vf, o[n], 0, 0, 0);
    }
  }

#pragma unroll
  for (int rr = 0; rr < 4; ++rr) {
    float inv = 1.0f / lrow[rr];
    int qrow = q0 + hi * 4 + rr;
#pragma unroll
    for (int n = 0; n < 8; ++n)
      ao[(size_t)(b * 2048 + qrow) * 2048 + h * 128 + n * 16 + r] = f2b(o[n][rr] * inv);
  }
}

extern "C" void kernel_launch(void* const* d_in, const int* in_sizes, int n_in,
                              void* d_out, int out_size, void* d_ws, size_t ws_size,
                              hipStream_t stream) {
  const float* x = (const float*)d_in[0];
  const float* fc = (const float*)d_in[1];
  const float* wq = (const float*)d_in[2];
  const float* wk = (const float*)d_in[3];
  const float* wv = (const float*)d_in[4];
  const float* wo = (const float*)d_in[5];
  const float* qw = (const float*)d_in[6];
  const float* kw = (const float*)d_in[7];
  float* out = (float*)d_out;
  char* ws = (char*)d_ws;

  u16* xb    = (u16*)(ws);                 // [4096][2048] bf16   16 MB
  u16* wqkvb = (u16*)(ws + 16777216);      // [4096][2048] bf16   16 MB  (wq|wk|wv rows)
  u16* wob   = (u16*)(ws + 33554432);      // [2048][2048] bf16    8 MB
  u16* qkv   = (u16*)(ws + 41943040);      // [4096][4096] bf16   32 MB
  u16* qrope = (u16*)(ws + 75497472);      // [2][16][2048][128]  16 MB
  u16* krope = (u16*)(ws + 92274688);      // [2][8][2048][128]    8 MB
  u16* vtb   = (u16*)(ws + 100663296);     // [2][8][128][2048]    8 MB
  u16* ao    = (u16*)(ws + 109051904);     // [4096][2048] bf16   16 MB

  cvt_f32_bf16<<<8192, 256, 0, stream>>>(x, xb, 2097152);
  cvt_f32_bf16<<<4096, 256, 0, stream>>>(wq, wqkvb, 1048576);
  cvt_f32_bf16<<<2048, 256, 0, stream>>>(wk, wqkvb + 2048 * 2048, 524288);
  cvt_f32_bf16<<<2048, 256, 0, stream>>>(wv, wqkvb + 3072 * 2048, 524288);
  cvt_f32_bf16<<<4096, 256, 0, stream>>>(wo, wob, 1048576);

  dim3 g1(32, 32);
  gemm_bt<0><<<g1, 256, 0, stream>>>(xb, wqkvb, (void*)qkv, 4096, 4096, 2048);

  rmsnorm_rope<<<24576, 256, 0, stream>>>(qkv, fc, qw, kw, qrope, krope);
  v_transpose<<<512, 256, 0, stream>>>(qkv, vtb);

  attn<<<1024, 256, 0, stream>>>(qrope, krope, vtb, ao);

  dim3 g2(32, 16);
  gemm_bt<1><<<g2, 256, 0, stream>>>(ao, wob, (void*)out, 4096, 2048, 2048);
}

// Round 2
// 264.120 us; speedup vs baseline: 2.5417x; 2.5417x over previous
//
#include <hip/hip_runtime.h>

#define B_ 2
#define S_ 2048
#define D_ 2048
#define NH 16
#define NKV 8
#define HD 128
#define SCALE 0.08838834764831845f
#define CEXP 0.1275255f          // SCALE * log2(e)
#define RTHR 62.733f             // 8 / CEXP  (defer-max threshold, p <= 2^8)

typedef unsigned short u16;
typedef __attribute__((ext_vector_type(8))) short short8;
typedef __attribute__((ext_vector_type(4))) float f32x4;
typedef __attribute__((ext_vector_type(4))) int i32x4;
typedef __attribute__((ext_vector_type(2))) int i32x2;

#define ASM_VMCNT(N) asm volatile("s_waitcnt vmcnt(" #N ")" ::: "memory")

__device__ __forceinline__ u16 f2b(float f) {
  union { float f; unsigned u; } c; c.f = f;
  unsigned u = c.u;
  return (u16)((u + 0x7fffu + ((u >> 16) & 1u)) >> 16);
}
__device__ __forceinline__ float b2f(u16 h) {
  union { unsigned u; float f; } c; c.u = ((unsigned)h) << 16;
  return c.f;
}
__device__ __forceinline__ float exp2f_fast(float x) {
  float r; asm("v_exp_f32 %0, %1" : "=v"(r) : "v"(x)); return r;
}
__device__ __forceinline__ int cvtpk(float a, float b) {  // low16=bf16(a), high16=bf16(b)
  int r; asm("v_cvt_pk_bf16_f32 %0, %1, %2" : "=v"(r) : "v"(a), "v"(b)); return r;
}

__device__ __forceinline__ void load_lds16(const u16* g, u16* l) {
  __builtin_amdgcn_global_load_lds(
      (const __attribute__((address_space(1))) unsigned int*)g,
      (__attribute__((address_space(3))) unsigned int*)l, 16, 0, 0);
}

// ---------------- f32 -> bf16 conversion ----------------
__global__ __launch_bounds__(256) void cvt_f32_bf16(const float* __restrict__ src,
                                                    u16* __restrict__ dst, int n4) {
  int i = blockIdx.x * 256 + threadIdx.x;
  if (i >= n4) return;
  float4 v = ((const float4*)src)[i];
  u16 o0 = f2b(v.x), o1 = f2b(v.y), o2 = f2b(v.z), o3 = f2b(v.w);
  unsigned long long packed = (unsigned long long)o0 | ((unsigned long long)o1 << 16) |
                              ((unsigned long long)o2 << 32) | ((unsigned long long)o3 << 48);
  ((unsigned long long*)dst)[i] = packed;
}

// ---------------- GEMM: C[M,N] = A[M,K] * B[N,K]^T (bf16 in, f32 acc) ----------------
template<int OUTF32>
__global__ __launch_bounds__(256) void gemm_bt(const u16* __restrict__ A, const u16* __restrict__ Bm,
                                               void* __restrict__ Cv, int M, int N, int K) {
  __shared__ __align__(16) u16 As[128 * 64];
  __shared__ __align__(16) u16 Bs[128 * 64];
  const int tid = threadIdx.x;
  const int wave = tid >> 6, lane = tid & 63;
  const int bm = blockIdx.x, bn = blockIdx.y;
  const int wr = wave >> 1, wc = wave & 1;
  const int r = lane & 15, hi = lane >> 4;

  f32x4 acc[4][4];
#pragma unroll
  for (int m = 0; m < 4; ++m)
#pragma unroll
    for (int n = 0; n < 4; ++n) acc[m][n] = (f32x4){0.f, 0.f, 0.f, 0.f};

  const int gslot = (lane & 7) ^ (lane >> 3);
  const int srow_in_chunk = lane >> 3;

  for (int k0 = 0; k0 < K; k0 += 64) {
#pragma unroll
    for (int jj = 0; jj < 4; ++jj) {
      int j = wave * 4 + jj;
      int row = j * 8 + srow_in_chunk;
      const u16* ga = A + (size_t)(bm * 128 + row) * K + k0 + gslot * 8;
      load_lds16(ga, &As[j * 512]);
      const u16* gb = Bm + (size_t)(bn * 128 + row) * K + k0 + gslot * 8;
      load_lds16(gb, &Bs[j * 512]);
    }
    __syncthreads();
#pragma unroll
    for (int kc = 0; kc < 2; ++kc) {
      short8 af[4], bfr[4];
#pragma unroll
      for (int m = 0; m < 4; ++m) {
        int row = wr * 64 + m * 16 + r;
        int slot = (hi + kc * 4) ^ (row & 7);
        af[m] = *(const short8*)&As[row * 64 + slot * 8];
      }
#pragma unroll
      for (int n = 0; n < 4; ++n) {
        int row = wc * 64 + n * 16 + r;
        int slot = (hi + kc * 4) ^ (row & 7);
        bfr[n] = *(const short8*)&Bs[row * 64 + slot * 8];
      }
#pragma unroll
      for (int m = 0; m < 4; ++m)
#pragma unroll
        for (int n = 0; n < 4; ++n)
          acc[m][n] = __builtin_amdgcn_mfma_f32_16x16x32_bf16(af[m], bfr[n], acc[m][n], 0, 0, 0);
    }
    __syncthreads();
  }

#pragma unroll
  for (int m = 0; m < 4; ++m)
#pragma unroll
    for (int n = 0; n < 4; ++n)
#pragma unroll
      for (int r2 = 0; r2 < 4; ++r2) {
        int grow = bm * 128 + wr * 64 + m * 16 + hi * 4 + r2;
        int gcol = bn * 128 + wc * 64 + n * 16 + r;
        if (OUTF32)
          ((float*)Cv)[(size_t)grow * N + gcol] = acc[m][n][r2];
        else
          ((u16*)Cv)[(size_t)grow * N + gcol] = f2b(acc[m][n][r2]);
      }
}

// ---------------- per-head RMSNorm + RoPE for Q and K ----------------
__global__ __launch_bounds__(256) void rmsnorm_rope(const u16* __restrict__ qkv, const float* __restrict__ fc,
                                                    const float* __restrict__ qw, const float* __restrict__ kw,
                                                    u16* __restrict__ qr, u16* __restrict__ kr) {
  const int tid = threadIdx.x, wave = tid >> 6, lane = tid & 63;
  const int rowid = blockIdx.x * 4 + wave;
  const int token = rowid / 24;
  const int hh = rowid % 24;
  const int b = token >> 11, s = token & 2047;
  const bool isq = hh < 16;
  const int off = isq ? hh * 128 : 2048 + (hh - 16) * 128;
  const u16* src = qkv + (size_t)token * 4096 + off + lane * 2;
  unsigned pv = *(const unsigned*)src;
  float t0 = b2f((u16)(pv & 0xffffu));
  float t1 = b2f((u16)(pv >> 16));
  float ss = t0 * t0 + t1 * t1;
#pragma unroll
  for (int mm = 1; mm < 64; mm <<= 1) ss += __shfl_xor(ss, mm, 64);
  float rms = rsqrtf(ss * (1.0f / 128.0f) + 1e-6f);
  const float* nw = isq ? qw : kw;
  t0 *= rms * nw[lane * 2];
  t1 *= rms * nw[lane * 2 + 1];
  float c = fc[(s * 64 + lane) * 2], sn = fc[(s * 64 + lane) * 2 + 1];
  float o0 = t0 * c - t1 * sn;
  float o1 = t0 * sn + t1 * c;
  unsigned ov = (unsigned)f2b(o0) | ((unsigned)f2b(o1) << 16);
  if (isq)
    *(unsigned*)(qr + ((size_t)(b * 16 + hh) * 2048 + s) * 128 + lane * 2) = ov;
  else
    *(unsigned*)(kr + ((size_t)(b * 8 + hh - 16) * 2048 + s) * 128 + lane * 2) = ov;
}

// ---------------- V transpose: qkv v-section -> vt[b][hkv][d][s] ----------------
__global__ __launch_bounds__(256) void v_transpose(const u16* __restrict__ qkv, u16* __restrict__ vt) {
  __shared__ __align__(16) u16 tile[64][136];
  const int blk = blockIdx.x;
  const int st = blk & 31, h = (blk >> 5) & 7, b = blk >> 8;
  const int s0 = st * 64, t = threadIdx.x;
#pragma unroll
  for (int p = 0; p < 4; ++p) {
    int row = p * 16 + (t >> 4), c8 = (t & 15) * 8;
    const u16* src = qkv + (size_t)(b * 2048 + s0 + row) * 4096 + 3072 + h * 128 + c8;
    *(short8*)&tile[row][c8] = *(const short8*)src;
  }
  __syncthreads();
  const int d = t >> 1, j0 = (t & 1) * 32;
  u16* dst = vt + ((size_t)(b * 8 + h) * 128 + d) * 2048 + s0 + j0;
#pragma unroll
  for (int j = 0; j < 32; j += 8) {
    short8 v;
#pragma unroll
    for (int u = 0; u < 8; ++u) v[u] = (short)tile[j0 + j + u][d];
    *(short8*)(dst + j) = v;
  }
}

// ---------------- causal flash attention v2 ----------------
// 4 waves x 32 q-rows = 128-row tile; KVBLK=64; K/V double-buffered LDS (XOR swizzled);
// swapped QK^T (S[kv][q]) + swapped PV (O[d][q]) -> lane-local softmax; in-reg P repack.
__global__ __launch_bounds__(256, 2) void attn2(const u16* __restrict__ qr, const u16* __restrict__ kr,
                                                const u16* __restrict__ vt, u16* __restrict__ ao) {
  __shared__ __align__(16) u16 Ks[2][64 * 128];
  __shared__ __align__(16) u16 Vs[2][128 * 64];
  const int tid = threadIdx.x, wave = tid >> 6, lane = tid & 63;
  const int r = lane & 15, hi = lane >> 4;

  // bijective XCD-chunk swizzle (512 % 8 == 0) + big-tile-first dispatch order
  const int wg = blockIdx.x;
  const int L = (wg & 7) * 64 + (wg >> 3);
  const int bh = L >> 4;
  const int t = 15 - (L & 15);
  const int b = bh >> 4, h = bh & 15, hkv = h >> 1;

  const u16* Q = qr + (size_t)(b * 16 + h) * S_ * HD;
  const u16* Kg = kr + (size_t)(b * 8 + hkv) * S_ * HD;
  const u16* Vg = vt + (size_t)(b * 8 + hkv) * HD * S_;

  const int q0w = t * 128 + wave * 32;
  const int nsteps = 2 * (t + 1);

  // Q fragments [c][qc]: lane r -> Q row q0w+qc*16+r, k-elems c*32+hi*8
  short8 qf[4][2];
#pragma unroll
  for (int c = 0; c < 4; ++c)
#pragma unroll
    for (int qc = 0; qc < 2; ++qc)
      qf[c][qc] = *(const short8*)(Q + (size_t)(q0w + qc * 16 + r) * HD + c * 32 + hi * 8);

  f32x4 o[8][2];
#pragma unroll
  for (int n = 0; n < 8; ++n)
#pragma unroll
    for (int qc = 0; qc < 2; ++qc) o[n][qc] = (f32x4){0.f, 0.f, 0.f, 0.f};
  float m[2] = {-1e30f, -1e30f}, l[2] = {0.f, 0.f};

  auto stage = [&](int buf, int kv0) {
#pragma unroll
    for (int inst = 0; inst < 4; ++inst) {
      int p = wave * 4096 + inst * 1024 + lane * 16;   // byte pos in 16KB K tile
      int row = p >> 8;                                // kv row (256B rows)
      int colb = (p & 255) ^ ((row & 7) << 4);         // inverse swizzle on SOURCE
      load_lds16(Kg + (((size_t)(kv0 + row)) << 7) + (colb >> 1),
                 &Ks[buf][(wave * 4096 + inst * 1024) >> 1]);
    }
#pragma unroll
    for (int inst = 0; inst < 4; ++inst) {
      int p = wave * 4096 + inst * 1024 + lane * 16;   // byte pos in 16KB V tile
      int d = p >> 7;                                  // d row (128B rows)
      int colb = (p & 127) ^ ((d & 7) << 4);
      load_lds16(Vg + (size_t)d * S_ + kv0 + (colb >> 1),
                 &Vs[buf][(wave * 4096 + inst * 1024) >> 1]);
    }
  };

  stage(0, 0);
  for (int i = 0; i < nsteps; ++i) {
    const int kv0 = i * 64;
    const u16* kb = Ks[i & 1];
    const u16* vb = Vs[i & 1];
    if (i + 1 < nsteps) {
      stage((i + 1) & 1, kv0 + 64);
      ASM_VMCNT(8);          // current buffers complete; next-tile loads stay in flight
    } else {
      ASM_VMCNT(0);
    }
    __builtin_amdgcn_sched_barrier(0);
    __builtin_amdgcn_s_barrier();
    __builtin_amdgcn_sched_barrier(0);

    if (kv0 < q0w + 32) {    // wave-uniform: not fully masked
      // ---- QK^T (swapped): sacc[kvsub][qc] = S[kv0+kvsub*16+hi*4+rr][q0w+qc*16+r]
      f32x4 sacc[4][2];
#pragma unroll
      for (int kvsub = 0; kvsub < 4; ++kvsub)
#pragma unroll
        for (int qc = 0; qc < 2; ++qc) sacc[kvsub][qc] = (f32x4){0.f, 0.f, 0.f, 0.f};
      const int swz = (r & 7) << 4;
#pragma unroll
      for (int kvsub = 0; kvsub < 4; ++kvsub) {
        const int krow = kvsub * 16 + r;
#pragma unroll
        for (int c = 0; c < 4; ++c) {
          short8 kf = *(const short8*)&kb[(krow << 7) + (((c * 64 + hi * 16) ^ swz) >> 1)];
          sacc[kvsub][0] = __builtin_amdgcn_mfma_f32_16x16x32_bf16(kf, qf[c][0], sacc[kvsub][0], 0, 0, 0);
          sacc[kvsub][1] = __builtin_amdgcn_mfma_f32_16x16x32_bf16(kf, qf[c][1], sacc[kvsub][1], 0, 0, 0);
        }
      }
      // ---- causal mask (diagonal step only)
      if (kv0 + 64 > q0w) {
#pragma unroll
        for (int qc = 0; qc < 2; ++qc) {
          const int q = q0w + qc * 16 + r;
#pragma unroll
          for (int kvsub = 0; kvsub < 4; ++kvsub) {
            const int kvb = kv0 + kvsub * 16 + hi * 4;
#pragma unroll
            for (int rr = 0; rr < 4; ++rr)
              sacc[kvsub][qc][rr] = (kvb + rr > q) ? -1e30f : sacc[kvsub][qc][rr];
          }
        }
      }
      // ---- online softmax (lane-local rows, 2 shfl per reduce)
      float mx[2];
#pragma unroll
      for (int qc = 0; qc < 2; ++qc) {
        float v = sacc[0][qc][0];
#pragma unroll
        for (int kvsub = 0; kvsub < 4; ++kvsub)
#pragma unroll
          for (int rr = 0; rr < 4; ++rr) v = fmaxf(v, sacc[kvsub][qc][rr]);
        v = fmaxf(v, __shfl_xor(v, 16, 64));
        v = fmaxf(v, __shfl_xor(v, 32, 64));
        mx[qc] = v;
      }
      bool need = (mx[0] > m[0] + RTHR) || (mx[1] > m[1] + RTHR);
      if (__any(need)) {
#pragma unroll
        for (int qc = 0; qc < 2; ++qc) {
          float mn = fmaxf(m[qc], mx[qc]);
          float sc = exp2f_fast((m[qc] - mn) * CEXP);
          l[qc] *= sc;
          m[qc] = mn;
#pragma unroll
          for (int n = 0; n < 8; ++n) o[n][qc] *= sc;
        }
      }
      int W[2][4][2];
#pragma unroll
      for (int qc = 0; qc < 2; ++qc) {
        const float mc = m[qc] * CEXP;
        float ps = 0.f;
#pragma unroll
        for (int kvsub = 0; kvsub < 4; ++kvsub) {
          float p0 = exp2f_fast(__builtin_fmaf(sacc[kvsub][qc][0], CEXP, -mc));
          float p1 = exp2f_fast(__builtin_fmaf(sacc[kvsub][qc][1], CEXP, -mc));
          float p2 = exp2f_fast(__builtin_fmaf(sacc[kvsub][qc][2], CEXP, -mc));
          float p3 = exp2f_fast(__builtin_fmaf(sacc[kvsub][qc][3], CEXP, -mc));
          ps += (p0 + p1) + (p2 + p3);
          W[qc][kvsub][0] = cvtpk(p0, p1);   // kv +0,+1
          W[qc][kvsub][1] = cvtpk(p2, p3);   // kv +2,+3
        }
        l[qc] += ps;
      }
      // ---- in-register P repack -> PV B-fragments (lane r: P[q][kv c'*32+hi*8 ..+8))
      short8 pf[2][2];
      const int idx0 = (r + ((hi & 1) << 5)) << 2;  // src lane (r, 2*(hi&1)) * 4
      const int idx1 = idx0 + 64;                   // src lane + 16
      const bool lo2 = (hi < 2);
#pragma unroll
      for (int cp = 0; cp < 2; ++cp)
#pragma unroll
        for (int qc = 0; qc < 2; ++qc) {
          int a0 = W[qc][2 * cp][0], a1 = W[qc][2 * cp][1];
          int b0 = W[qc][2 * cp + 1][0], b1 = W[qc][2 * cp + 1][1];
          int e0 = __builtin_amdgcn_ds_bpermute(idx0, a0);
          int f0 = __builtin_amdgcn_ds_bpermute(idx0, b0);
          int e1 = __builtin_amdgcn_ds_bpermute(idx0, a1);
          int f1 = __builtin_amdgcn_ds_bpermute(idx0, b1);
          int e2 = __builtin_amdgcn_ds_bpermute(idx1, a0);
          int f2 = __builtin_amdgcn_ds_bpermute(idx1, b0);
          int e3 = __builtin_amdgcn_ds_bpermute(idx1, a1);
          int f3 = __builtin_amdgcn_ds_bpermute(idx1, b1);
          i32x4 v = (i32x4){lo2 ? e0 : f0, lo2 ? e1 : f1, lo2 ? e2 : f2, lo2 ? e3 : f3};
          pf[cp][qc] = *(short8*)&v;
        }
      // ---- PV (swapped): o[n][qc] = O[d=n*16+hi*4+rr][q0w+qc*16+r]
#pragma unroll
      for (int n = 0; n < 8; ++n) {
        const int d = n * 16 + r;
#pragma unroll
        for (int cp = 0; cp < 2; ++cp) {
          short8 vf = *(const short8*)&vb[(d << 6) + (((cp * 64 + hi * 16) ^ swz) >> 1)];
          o[n][0] = __builtin_amdgcn_mfma_f32_16x16x32_bf16(vf, pf[cp][0], o[n][0], 0, 0, 0);
          o[n][1] = __builtin_amdgcn_mfma_f32_16x16x32_bf16(vf, pf[cp][1], o[n][1], 0, 0, 0);
        }
      }
    }
    __builtin_amdgcn_sched_barrier(0);
    __builtin_amdgcn_s_barrier();   // buffer consumed; next iter may overwrite
    __builtin_amdgcn_sched_barrier(0);
  }

  // ---- epilogue: normalize, pack 4 consecutive d as bf16, 8B stores
#pragma unroll
  for (int qc = 0; qc < 2; ++qc) {
    float lt = l[qc];
    lt += __shfl_xor(lt, 16, 64);
    lt += __shfl_xor(lt, 32, 64);
    float inv = 1.0f / lt;
    const size_t rowoff = ((size_t)(b * 2048 + q0w + qc * 16 + r)) * 2048 + h * 128;
#pragma unroll
    for (int n = 0; n < 8; ++n) {
      int w0 = cvtpk(o[n][qc][0] * inv, o[n][qc][1] * inv);
      int w1 = cvtpk(o[n][qc][2] * inv, o[n][qc][3] * inv);
      i32x2 pk = (i32x2){w0, w1};
      *(i32x2*)((u16*)ao + rowoff + n * 16 + hi * 4) = pk;
    }
  }
}

extern "C" void kernel_launch(void* const* d_in, const int* in_sizes, int n_in,
                              void* d_out, int out_size, void* d_ws, size_t ws_size,
                              hipStream_t stream) {
  const float* x = (const float*)d_in[0];
  const float* fc = (const float*)d_in[1];
  const float* wq = (const float*)d_in[2];
  const float* wk = (const float*)d_in[3];
  const float* wv = (const float*)d_in[4];
  const float* wo = (const float*)d_in[5];
  const float* qw = (const float*)d_in[6];
  const float* kw = (const float*)d_in[7];
  float* out = (float*)d_out;
  char* ws = (char*)d_ws;

  u16* xb    = (u16*)(ws);                 // [4096][2048] bf16   16 MB
  u16* wqkvb = (u16*)(ws + 16777216);      // [4096][2048] bf16   16 MB
  u16* wob   = (u16*)(ws + 33554432);      // [2048][2048] bf16    8 MB
  u16* qkv   = (u16*)(ws + 41943040);      // [4096][4096] bf16   32 MB
  u16* qrope = (u16*)(ws + 75497472);      // [2][16][2048][128]  16 MB
  u16* krope = (u16*)(ws + 92274688);      // [2][8][2048][128]    8 MB
  u16* vtb   = (u16*)(ws + 100663296);     // [2][8][128][2048]    8 MB
  u16* ao    = (u16*)(ws + 109051904);     // [4096][2048] bf16   16 MB

  cvt_f32_bf16<<<8192, 256, 0, stream>>>(x, xb, 2097152);
  cvt_f32_bf16<<<4096, 256, 0, stream>>>(wq, wqkvb, 1048576);
  cvt_f32_bf16<<<2048, 256, 0, stream>>>(wk, wqkvb + 2048 * 2048, 524288);
  cvt_f32_bf16<<<2048, 256, 0, stream>>>(wv, wqkvb + 3072 * 2048, 524288);
  cvt_f32_bf16<<<4096, 256, 0, stream>>>(wo, wob, 1048576);

  dim3 g1(32, 32);
  gemm_bt<0><<<g1, 256, 0, stream>>>(xb, wqkvb, (void*)qkv, 4096, 4096, 2048);

  rmsnorm_rope<<<24576, 256, 0, stream>>>(qkv, fc, qw, kw, qrope, krope);
  v_transpose<<<512, 256, 0, stream>>>(qkv, vtb);

  attn2<<<512, 256, 0, stream>>>(qrope, krope, vtb, ao);

  dim3 g2(32, 16);
  gemm_bt<1><<<g2, 256, 0, stream>>>(ao, wob, (void*)out, 4096, 2048, 2048);
}

// Round 3
// 254.041 us; speedup vs baseline: 2.6425x; 1.0397x over previous
//
#include <hip/hip_runtime.h>

#define B_ 2
#define S_ 2048
#define D_ 2048
#define NH 16
#define NKV 8
#define HD 128
#define SCALE 0.08838834764831845f
#define CEXP 0.1275255f          // SCALE * log2(e)
#define RTHR 62.733f             // 8 / CEXP  (defer-max threshold, p <= 2^8)

typedef unsigned short u16;
typedef __attribute__((ext_vector_type(8))) short short8;
typedef __attribute__((ext_vector_type(4))) float f32x4;
typedef __attribute__((ext_vector_type(4))) int i32x4;
typedef __attribute__((ext_vector_type(2))) int i32x2;

#define ASM_VMCNT(N) asm volatile("s_waitcnt vmcnt(" #N ")" ::: "memory")

__device__ __forceinline__ u16 f2b(float f) {
  union { float f; unsigned u; } c; c.f = f;
  unsigned u = c.u;
  return (u16)((u + 0x7fffu + ((u >> 16) & 1u)) >> 16);
}
__device__ __forceinline__ float b2f(u16 h) {
  union { unsigned u; float f; } c; c.u = ((unsigned)h) << 16;
  return c.f;
}
__device__ __forceinline__ float exp2f_fast(float x) {
  float r; asm("v_exp_f32 %0, %1" : "=v"(r) : "v"(x)); return r;
}
__device__ __forceinline__ int cvtpk(float a, float b) {  // low16=bf16(a), high16=bf16(b)
  int r; asm("v_cvt_pk_bf16_f32 %0, %1, %2" : "=v"(r) : "v"(a), "v"(b)); return r;
}

__device__ __forceinline__ void load_lds16(const u16* g, u16* l) {
  __builtin_amdgcn_global_load_lds(
      (const __attribute__((address_space(1))) unsigned int*)g,
      (__attribute__((address_space(3))) unsigned int*)l, 16, 0, 0);
}

// ---------------- fused f32 -> bf16 conversion (all 5 tensors, 1 launch) ----------------
__global__ __launch_bounds__(256) void cvt_all(const float* __restrict__ x,
                                               const float* __restrict__ wq,
                                               const float* __restrict__ wk,
                                               const float* __restrict__ wv,
                                               const float* __restrict__ wo,
                                               u16* __restrict__ xb,
                                               u16* __restrict__ wqkvb,
                                               u16* __restrict__ wob) {
  const int blk = blockIdx.x;
  const float* src; u16* dst; int base;
  if (blk < 8192)       { src = x;  dst = xb;                  base = blk; }
  else if (blk < 12288) { src = wq; dst = wqkvb;               base = blk - 8192; }
  else if (blk < 14336) { src = wk; dst = wqkvb + 2048 * 2048; base = blk - 12288; }
  else if (blk < 16384) { src = wv; dst = wqkvb + 3072 * 2048; base = blk - 14336; }
  else                  { src = wo; dst = wob;                 base = blk - 16384; }
  int i = base * 256 + threadIdx.x;
  float4 v = ((const float4*)src)[i];
  u16 o0 = f2b(v.x), o1 = f2b(v.y), o2 = f2b(v.z), o3 = f2b(v.w);
  unsigned long long packed = (unsigned long long)o0 | ((unsigned long long)o1 << 16) |
                              ((unsigned long long)o2 << 32) | ((unsigned long long)o3 << 48);
  ((unsigned long long*)dst)[i] = packed;
}

// ---------------- GEMM: C[M,N] = A[M,K] * B[N,K]^T (bf16 in, f32 acc) ----------------
template<int OUTF32>
__global__ __launch_bounds__(256) void gemm_bt(const u16* __restrict__ A, const u16* __restrict__ Bm,
                                               void* __restrict__ Cv, int M, int N, int K) {
  __shared__ __align__(16) u16 As[128 * 64];
  __shared__ __align__(16) u16 Bs[128 * 64];
  const int tid = threadIdx.x;
  const int wave = tid >> 6, lane = tid & 63;
  const int bm = blockIdx.x, bn = blockIdx.y;
  const int wr = wave >> 1, wc = wave & 1;
  const int r = lane & 15, hi = lane >> 4;

  f32x4 acc[4][4];
#pragma unroll
  for (int m = 0; m < 4; ++m)
#pragma unroll
    for (int n = 0; n < 4; ++n) acc[m][n] = (f32x4){0.f, 0.f, 0.f, 0.f};

  const int gslot = (lane & 7) ^ (lane >> 3);
  const int srow_in_chunk = lane >> 3;

  for (int k0 = 0; k0 < K; k0 += 64) {
#pragma unroll
    for (int jj = 0; jj < 4; ++jj) {
      int j = wave * 4 + jj;
      int row = j * 8 + srow_in_chunk;
      const u16* ga = A + (size_t)(bm * 128 + row) * K + k0 + gslot * 8;
      load_lds16(ga, &As[j * 512]);
      const u16* gb = Bm + (size_t)(bn * 128 + row) * K + k0 + gslot * 8;
      load_lds16(gb, &Bs[j * 512]);
    }
    __syncthreads();
#pragma unroll
    for (int kc = 0; kc < 2; ++kc) {
      short8 af[4], bfr[4];
#pragma unroll
      for (int m = 0; m < 4; ++m) {
        int row = wr * 64 + m * 16 + r;
        int slot = (hi + kc * 4) ^ (row & 7);
        af[m] = *(const short8*)&As[row * 64 + slot * 8];
      }
#pragma unroll
      for (int n = 0; n < 4; ++n) {
        int row = wc * 64 + n * 16 + r;
        int slot = (hi + kc * 4) ^ (row & 7);
        bfr[n] = *(const short8*)&Bs[row * 64 + slot * 8];
      }
#pragma unroll
      for (int m = 0; m < 4; ++m)
#pragma unroll
        for (int n = 0; n < 4; ++n)
          acc[m][n] = __builtin_amdgcn_mfma_f32_16x16x32_bf16(af[m], bfr[n], acc[m][n], 0, 0, 0);
    }
    __syncthreads();
  }

#pragma unroll
  for (int m = 0; m < 4; ++m)
#pragma unroll
    for (int n = 0; n < 4; ++n)
#pragma unroll
      for (int r2 = 0; r2 < 4; ++r2) {
        int grow = bm * 128 + wr * 64 + m * 16 + hi * 4 + r2;
        int gcol = bn * 128 + wc * 64 + n * 16 + r;
        if (OUTF32)
          ((float*)Cv)[(size_t)grow * N + gcol] = acc[m][n][r2];
        else
          ((u16*)Cv)[(size_t)grow * N + gcol] = f2b(acc[m][n][r2]);
      }
}

// ---------------- per-head RMSNorm + RoPE for Q and K ----------------
__global__ __launch_bounds__(256) void rmsnorm_rope(const u16* __restrict__ qkv, const float* __restrict__ fc,
                                                    const float* __restrict__ qw, const float* __restrict__ kw,
                                                    u16* __restrict__ qr, u16* __restrict__ kr) {
  const int tid = threadIdx.x, wave = tid >> 6, lane = tid & 63;
  const int rowid = blockIdx.x * 4 + wave;
  const int token = rowid / 24;
  const int hh = rowid % 24;
  const int b = token >> 11, s = token & 2047;
  const bool isq = hh < 16;
  const int off = isq ? hh * 128 : 2048 + (hh - 16) * 128;
  const u16* src = qkv + (size_t)token * 4096 + off + lane * 2;
  unsigned pv = *(const unsigned*)src;
  float t0 = b2f((u16)(pv & 0xffffu));
  float t1 = b2f((u16)(pv >> 16));
  float ss = t0 * t0 + t1 * t1;
#pragma unroll
  for (int mm = 1; mm < 64; mm <<= 1) ss += __shfl_xor(ss, mm, 64);
  float rms = rsqrtf(ss * (1.0f / 128.0f) + 1e-6f);
  const float* nw = isq ? qw : kw;
  t0 *= rms * nw[lane * 2];
  t1 *= rms * nw[lane * 2 + 1];
  float c = fc[(s * 64 + lane) * 2], sn = fc[(s * 64 + lane) * 2 + 1];
  float o0 = t0 * c - t1 * sn;
  float o1 = t0 * sn + t1 * c;
  unsigned ov = (unsigned)f2b(o0) | ((unsigned)f2b(o1) << 16);
  if (isq)
    *(unsigned*)(qr + ((size_t)(b * 16 + hh) * 2048 + s) * 128 + lane * 2) = ov;
  else
    *(unsigned*)(kr + ((size_t)(b * 8 + hh - 16) * 2048 + s) * 128 + lane * 2) = ov;
}

// ---------------- V transpose: qkv v-section -> vt[b][hkv][d][s]; also zeroes attn ctr ----------------
__global__ __launch_bounds__(256) void v_transpose(const u16* __restrict__ qkv, u16* __restrict__ vt,
                                                   int* __restrict__ ctr) {
  if (blockIdx.x == 0 && threadIdx.x == 0) *ctr = 0;  // runs before attn (stream order)
  __shared__ __align__(16) u16 tile[64][136];
  const int blk = blockIdx.x;
  const int st = blk & 31, h = (blk >> 5) & 7, b = blk >> 8;
  const int s0 = st * 64, t = threadIdx.x;
#pragma unroll
  for (int p = 0; p < 4; ++p) {
    int row = p * 16 + (t >> 4), c8 = (t & 15) * 8;
    const u16* src = qkv + (size_t)(b * 2048 + s0 + row) * 4096 + 3072 + h * 128 + c8;
    *(short8*)&tile[row][c8] = *(const short8*)src;
  }
  __syncthreads();
  const int d = t >> 1, j0 = (t & 1) * 32;
  u16* dst = vt + ((size_t)(b * 8 + h) * 128 + d) * 2048 + s0 + j0;
#pragma unroll
  for (int j = 0; j < 32; j += 8) {
    short8 v;
#pragma unroll
    for (int u = 0; u < 8; ++u) v[u] = (short)tile[j0 + j + u][d];
    *(short8*)(dst + j) = v;
  }
}

// ---------------- causal flash attention v3: persistent blocks + dynamic tile queue ----------------
// 4 waves x 32 q-rows = 128-row tile; KVBLK=64; K/V double-buffered LDS (XOR swizzled);
// swapped QK^T (S[kv][q]) + swapped PV (O[d][q]); in-reg P repack; big-tile-first work queue.
__global__ __launch_bounds__(256, 2) void attn3(const u16* __restrict__ qr, const u16* __restrict__ kr,
                                                const u16* __restrict__ vt, u16* __restrict__ ao,
                                                int* __restrict__ ctr) {
  __shared__ __align__(16) u16 Ks[2][64 * 128];
  __shared__ __align__(16) u16 Vs[2][128 * 64];
  __shared__ int tileno;
  const int tid = threadIdx.x, wave = tid >> 6, lane = tid & 63;
  const int r = lane & 15, hi = lane >> 4;
  const int swz = (r & 7) << 4;

  for (;;) {
    if (tid == 0) tileno = atomicAdd(ctr, 1);
    __syncthreads();
    const int n = tileno;
    if (n >= 512) break;
    // big-tile-first: first 32 grabs are the t=15 tiles (32 steps each)
    const int t = 15 - (n >> 5);
    const int bh = n & 31;
    const int b = bh >> 4, h = bh & 15, hkv = h >> 1;

    const u16* Q  = qr + (size_t)(b * 16 + h) * S_ * HD;
    const u16* Kg = kr + (size_t)(b * 8 + hkv) * S_ * HD;
    const u16* Vg = vt + (size_t)(b * 8 + hkv) * HD * S_;

    const int q0w = t * 128 + wave * 32;
    const int nsteps = 2 * (t + 1);

    // Q fragments [c][qc]: lane r -> Q row q0w+qc*16+r, k-elems c*32+hi*8
    short8 qf[4][2];
#pragma unroll
    for (int c = 0; c < 4; ++c)
#pragma unroll
      for (int qc = 0; qc < 2; ++qc)
        qf[c][qc] = *(const short8*)(Q + (size_t)(q0w + qc * 16 + r) * HD + c * 32 + hi * 8);

    f32x4 o[8][2];
#pragma unroll
    for (int nn = 0; nn < 8; ++nn)
#pragma unroll
      for (int qc = 0; qc < 2; ++qc) o[nn][qc] = (f32x4){0.f, 0.f, 0.f, 0.f};
    float m[2] = {-1e30f, -1e30f}, l[2] = {0.f, 0.f};

    auto stage = [&](int buf, int kv0) {
#pragma unroll
      for (int inst = 0; inst < 4; ++inst) {
        int p = wave * 4096 + inst * 1024 + lane * 16;   // byte pos in 16KB K tile
        int row = p >> 8;                                // kv row (256B rows)
        int colb = (p & 255) ^ ((row & 7) << 4);         // inverse swizzle on SOURCE
        load_lds16(Kg + (((size_t)(kv0 + row)) << 7) + (colb >> 1),
                   &Ks[buf][(wave * 4096 + inst * 1024) >> 1]);
      }
#pragma unroll
      for (int inst = 0; inst < 4; ++inst) {
        int p = wave * 4096 + inst * 1024 + lane * 16;   // byte pos in 16KB V tile
        int d = p >> 7;                                  // d row (128B rows)
        int colb = (p & 127) ^ ((d & 7) << 4);
        load_lds16(Vg + (size_t)d * S_ + kv0 + (colb >> 1),
                   &Vs[buf][(wave * 4096 + inst * 1024) >> 1]);
      }
    };

    stage(0, 0);
    for (int i = 0; i < nsteps; ++i) {
      const int kv0 = i * 64;
      const u16* kb = Ks[i & 1];
      const u16* vb = Vs[i & 1];
      if (i + 1 < nsteps) {
        stage((i + 1) & 1, kv0 + 64);
        ASM_VMCNT(8);          // current buffers complete; next-tile loads stay in flight
      } else {
        ASM_VMCNT(0);
      }
      __builtin_amdgcn_sched_barrier(0);
      __builtin_amdgcn_s_barrier();
      __builtin_amdgcn_sched_barrier(0);

      if (kv0 < q0w + 32) {    // wave-uniform: not fully masked
        // ---- QK^T (swapped): sacc[kvsub][qc] = S[kv0+kvsub*16+hi*4+rr][q0w+qc*16+r]
        f32x4 sacc[4][2];
#pragma unroll
        for (int kvsub = 0; kvsub < 4; ++kvsub)
#pragma unroll
          for (int qc = 0; qc < 2; ++qc) sacc[kvsub][qc] = (f32x4){0.f, 0.f, 0.f, 0.f};
        __builtin_amdgcn_s_setprio(1);
#pragma unroll
        for (int kvsub = 0; kvsub < 4; ++kvsub) {
          const int krow = kvsub * 16 + r;
#pragma unroll
          for (int c = 0; c < 4; ++c) {
            short8 kf = *(const short8*)&kb[(krow << 7) + (((c * 64 + hi * 16) ^ swz) >> 1)];
            sacc[kvsub][0] = __builtin_amdgcn_mfma_f32_16x16x32_bf16(kf, qf[c][0], sacc[kvsub][0], 0, 0, 0);
            sacc[kvsub][1] = __builtin_amdgcn_mfma_f32_16x16x32_bf16(kf, qf[c][1], sacc[kvsub][1], 0, 0, 0);
          }
        }
        __builtin_amdgcn_s_setprio(0);
        // ---- causal mask (diagonal step only)
        if (kv0 + 64 > q0w) {
#pragma unroll
          for (int qc = 0; qc < 2; ++qc) {
            const int q = q0w + qc * 16 + r;
#pragma unroll
            for (int kvsub = 0; kvsub < 4; ++kvsub) {
              const int kvb = kv0 + kvsub * 16 + hi * 4;
#pragma unroll
              for (int rr = 0; rr < 4; ++rr)
                sacc[kvsub][qc][rr] = (kvb + rr > q) ? -1e30f : sacc[kvsub][qc][rr];
            }
          }
        }
        // ---- online softmax (lane-local rows, 2 shfl per reduce)
        float mx[2];
#pragma unroll
        for (int qc = 0; qc < 2; ++qc) {
          float v = sacc[0][qc][0];
#pragma unroll
          for (int kvsub = 0; kvsub < 4; ++kvsub)
#pragma unroll
            for (int rr = 0; rr < 4; ++rr) v = fmaxf(v, sacc[kvsub][qc][rr]);
          v = fmaxf(v, __shfl_xor(v, 16, 64));
          v = fmaxf(v, __shfl_xor(v, 32, 64));
          mx[qc] = v;
        }
        bool need = (mx[0] > m[0] + RTHR) || (mx[1] > m[1] + RTHR);
        if (__any(need)) {
#pragma unroll
          for (int qc = 0; qc < 2; ++qc) {
            float mn = fmaxf(m[qc], mx[qc]);
            float sc = exp2f_fast((m[qc] - mn) * CEXP);
            l[qc] *= sc;
            m[qc] = mn;
#pragma unroll
            for (int nn = 0; nn < 8; ++nn) o[nn][qc] *= sc;
          }
        }
        int W[2][4][2];
#pragma unroll
        for (int qc = 0; qc < 2; ++qc) {
          const float mc = m[qc] * CEXP;
          float ps = 0.f;
#pragma unroll
          for (int kvsub = 0; kvsub < 4; ++kvsub) {
            float p0 = exp2f_fast(__builtin_fmaf(sacc[kvsub][qc][0], CEXP, -mc));
            float p1 = exp2f_fast(__builtin_fmaf(sacc[kvsub][qc][1], CEXP, -mc));
            float p2 = exp2f_fast(__builtin_fmaf(sacc[kvsub][qc][2], CEXP, -mc));
            float p3 = exp2f_fast(__builtin_fmaf(sacc[kvsub][qc][3], CEXP, -mc));
            ps += (p0 + p1) + (p2 + p3);
            W[qc][kvsub][0] = cvtpk(p0, p1);   // kv +0,+1
            W[qc][kvsub][1] = cvtpk(p2, p3);   // kv +2,+3
          }
          l[qc] += ps;
        }
        // ---- in-register P repack -> PV B-fragments
        short8 pf[2][2];
        const int idx0 = (r + ((hi & 1) << 5)) << 2;  // src lane (r, 2*(hi&1)) * 4
        const int idx1 = idx0 + 64;                   // src lane + 16
        const bool lo2 = (hi < 2);
#pragma unroll
        for (int cp = 0; cp < 2; ++cp)
#pragma unroll
          for (int qc = 0; qc < 2; ++qc) {
            int a0 = W[qc][2 * cp][0], a1 = W[qc][2 * cp][1];
            int b0 = W[qc][2 * cp + 1][0], b1 = W[qc][2 * cp + 1][1];
            int e0 = __builtin_amdgcn_ds_bpermute(idx0, a0);
            int f0 = __builtin_amdgcn_ds_bpermute(idx0, b0);
            int e1 = __builtin_amdgcn_ds_bpermute(idx0, a1);
            int f1 = __builtin_amdgcn_ds_bpermute(idx0, b1);
            int e2 = __builtin_amdgcn_ds_bpermute(idx1, a0);
            int f2 = __builtin_amdgcn_ds_bpermute(idx1, b0);
            int e3 = __builtin_amdgcn_ds_bpermute(idx1, a1);
            int f3 = __builtin_amdgcn_ds_bpermute(idx1, b1);
            i32x4 v = (i32x4){lo2 ? e0 : f0, lo2 ? e1 : f1, lo2 ? e2 : f2, lo2 ? e3 : f3};
            pf[cp][qc] = *(short8*)&v;
          }
        // ---- PV (swapped): o[n][qc] = O[d=n*16+hi*4+rr][q0w+qc*16+r]
        __builtin_amdgcn_s_setprio(1);
#pragma unroll
        for (int nn = 0; nn < 8; ++nn) {
          const int d = nn * 16 + r;
#pragma unroll
          for (int cp = 0; cp < 2; ++cp) {
            short8 vf = *(const short8*)&vb[(d << 6) + (((cp * 64 + hi * 16) ^ swz) >> 1)];
            o[nn][0] = __builtin_amdgcn_mfma_f32_16x16x32_bf16(vf, pf[cp][0], o[nn][0], 0, 0, 0);
            o[nn][1] = __builtin_amdgcn_mfma_f32_16x16x32_bf16(vf, pf[cp][1], o[nn][1], 0, 0, 0);
          }
        }
        __builtin_amdgcn_s_setprio(0);
      }
      __builtin_amdgcn_sched_barrier(0);
      __builtin_amdgcn_s_barrier();   // buffer consumed; next iter may overwrite
      __builtin_amdgcn_sched_barrier(0);
    }

    // ---- epilogue: normalize, pack 4 consecutive d as bf16, 8B stores
#pragma unroll
    for (int qc = 0; qc < 2; ++qc) {
      float lt = l[qc];
      lt += __shfl_xor(lt, 16, 64);
      lt += __shfl_xor(lt, 32, 64);
      float inv = 1.0f / lt;
      const size_t rowoff = ((size_t)(b * 2048 + q0w + qc * 16 + r)) * 2048 + h * 128;
#pragma unroll
      for (int nn = 0; nn < 8; ++nn) {
        int w0 = cvtpk(o[nn][qc][0] * inv, o[nn][qc][1] * inv);
        int w1 = cvtpk(o[nn][qc][2] * inv, o[nn][qc][3] * inv);
        i32x2 pk = (i32x2){w0, w1};
        *(i32x2*)((u16*)ao + rowoff + nn * 16 + hi * 4) = pk;
      }
    }
    __syncthreads();  // all waves done with LDS before next tile's stage(0)
  }
}

extern "C" void kernel_launch(void* const* d_in, const int* in_sizes, int n_in,
                              void* d_out, int out_size, void* d_ws, size_t ws_size,
                              hipStream_t stream) {
  const float* x = (const float*)d_in[0];
  const float* fc = (const float*)d_in[1];
  const float* wq = (const float*)d_in[2];
  const float* wk = (const float*)d_in[3];
  const float* wv = (const float*)d_in[4];
  const float* wo = (const float*)d_in[5];
  const float* qw = (const float*)d_in[6];
  const float* kw = (const float*)d_in[7];
  float* out = (float*)d_out;
  char* ws = (char*)d_ws;

  u16* xb    = (u16*)(ws);                 // [4096][2048] bf16   16 MB
  u16* wqkvb = (u16*)(ws + 16777216);      // [4096][2048] bf16   16 MB
  u16* wob   = (u16*)(ws + 33554432);      // [2048][2048] bf16    8 MB
  u16* qkv   = (u16*)(ws + 41943040);      // [4096][4096] bf16   32 MB
  u16* qrope = (u16*)(ws + 75497472);      // [2][16][2048][128]  16 MB
  u16* krope = (u16*)(ws + 92274688);      // [2][8][2048][128]    8 MB
  u16* vtb   = (u16*)(ws + 100663296);     // [2][8][128][2048]    8 MB
  u16* ao    = (u16*)(ws + 109051904);     // [4096][2048] bf16   16 MB
  int* ctr   = (int*)qkv;                  // dead after v_transpose; zeroed there

  cvt_all<<<20480, 256, 0, stream>>>(x, wq, wk, wv, wo, xb, wqkvb, wob);

  dim3 g1(32, 32);
  gemm_bt<0><<<g1, 256, 0, stream>>>(xb, wqkvb, (void*)qkv, 4096, 4096, 2048);

  rmsnorm_rope<<<24576, 256, 0, stream>>>(qkv, fc, qw, kw, qrope, krope);
  v_transpose<<<512, 256, 0, stream>>>(qkv, vtb, ctr);

  attn3<<<448, 256, 0, stream>>>(qrope, krope, vtb, ao, ctr);

  dim3 g2(32, 16);
  gemm_bt<1><<<g2, 256, 0, stream>>>(ao, wob, (void*)out, 4096, 2048, 2048);
}

// Round 4
// 243.166 us; speedup vs baseline: 2.7607x; 1.0447x over previous
//
#include <hip/hip_runtime.h>

#define B_ 2
#define S_ 2048
#define D_ 2048
#define NH 16
#define NKV 8
#define HD 128
#define SCALE 0.08838834764831845f
#define CEXP 0.1275255f          // SCALE * log2(e)
#define RTHR 62.733f             // 8 / CEXP  (defer-max threshold, p <= 2^8)

typedef unsigned short u16;
typedef __attribute__((ext_vector_type(8))) short short8;
typedef __attribute__((ext_vector_type(4))) float f32x4;
typedef __attribute__((ext_vector_type(16))) float f32x16;
typedef __attribute__((ext_vector_type(4))) int i32x4;
typedef __attribute__((ext_vector_type(2))) int i32x2;

#define ASM_VMCNT(N) asm volatile("s_waitcnt vmcnt(" #N ")" ::: "memory")

__device__ __forceinline__ u16 f2b(float f) {
  union { float f; unsigned u; } c; c.f = f;
  unsigned u = c.u;
  return (u16)((u + 0x7fffu + ((u >> 16) & 1u)) >> 16);
}
__device__ __forceinline__ float b2f(u16 h) {
  union { unsigned u; float f; } c; c.u = ((unsigned)h) << 16;
  return c.f;
}
__device__ __forceinline__ float exp2f_fast(float x) {
  float r; asm("v_exp_f32 %0, %1" : "=v"(r) : "v"(x)); return r;
}
__device__ __forceinline__ int cvtpk(float a, float b) {  // low16=bf16(a), high16=bf16(b)
  int r; asm("v_cvt_pk_bf16_f32 %0, %1, %2" : "=v"(r) : "v"(a), "v"(b)); return r;
}
// swap: a.hi32lanes <-> b.lo32lanes (both regs updated)
__device__ __forceinline__ void pl32swap(int& a, int& b) {
  asm volatile("v_permlane32_swap_b32 %0, %1" : "+v"(a), "+v"(b));
}

__device__ __forceinline__ void load_lds16(const u16* g, u16* l) {
  __builtin_amdgcn_global_load_lds(
      (const __attribute__((address_space(1))) unsigned int*)g,
      (__attribute__((address_space(3))) unsigned int*)l, 16, 0, 0);
}

// ---------------- fused f32 -> bf16 conversion (all 5 tensors, 1 launch) ----------------
__global__ __launch_bounds__(256) void cvt_all(const float* __restrict__ x,
                                               const float* __restrict__ wq,
                                               const float* __restrict__ wk,
                                               const float* __restrict__ wv,
                                               const float* __restrict__ wo,
                                               u16* __restrict__ xb,
                                               u16* __restrict__ wqkvb,
                                               u16* __restrict__ wob) {
  const int blk = blockIdx.x;
  const float* src; u16* dst; int base;
  if (blk < 8192)       { src = x;  dst = xb;                  base = blk; }
  else if (blk < 12288) { src = wq; dst = wqkvb;               base = blk - 8192; }
  else if (blk < 14336) { src = wk; dst = wqkvb + 2048 * 2048; base = blk - 12288; }
  else if (blk < 16384) { src = wv; dst = wqkvb + 3072 * 2048; base = blk - 14336; }
  else                  { src = wo; dst = wob;                 base = blk - 16384; }
  int i = base * 256 + threadIdx.x;
  float4 v = ((const float4*)src)[i];
  u16 o0 = f2b(v.x), o1 = f2b(v.y), o2 = f2b(v.z), o3 = f2b(v.w);
  unsigned long long packed = (unsigned long long)o0 | ((unsigned long long)o1 << 16) |
                              ((unsigned long long)o2 << 32) | ((unsigned long long)o3 << 48);
  ((unsigned long long*)dst)[i] = packed;
}

// ---------------- GEMM: C[M,N] = A[M,K] * B[N,K]^T (bf16 in, f32 acc) ----------------
template<int OUTF32>
__global__ __launch_bounds__(256) void gemm_bt(const u16* __restrict__ A, const u16* __restrict__ Bm,
                                               void* __restrict__ Cv, int M, int N, int K) {
  __shared__ __align__(16) u16 As[128 * 64];
  __shared__ __align__(16) u16 Bs[128 * 64];
  const int tid = threadIdx.x;
  const int wave = tid >> 6, lane = tid & 63;
  const int bm = blockIdx.x, bn = blockIdx.y;
  const int wr = wave >> 1, wc = wave & 1;
  const int r = lane & 15, hi = lane >> 4;

  f32x4 acc[4][4];
#pragma unroll
  for (int m = 0; m < 4; ++m)
#pragma unroll
    for (int n = 0; n < 4; ++n) acc[m][n] = (f32x4){0.f, 0.f, 0.f, 0.f};

  const int gslot = (lane & 7) ^ (lane >> 3);
  const int srow_in_chunk = lane >> 3;

  for (int k0 = 0; k0 < K; k0 += 64) {
#pragma unroll
    for (int jj = 0; jj < 4; ++jj) {
      int j = wave * 4 + jj;
      int row = j * 8 + srow_in_chunk;
      const u16* ga = A + (size_t)(bm * 128 + row) * K + k0 + gslot * 8;
      load_lds16(ga, &As[j * 512]);
      const u16* gb = Bm + (size_t)(bn * 128 + row) * K + k0 + gslot * 8;
      load_lds16(gb, &Bs[j * 512]);
    }
    __syncthreads();
#pragma unroll
    for (int kc = 0; kc < 2; ++kc) {
      short8 af[4], bfr[4];
#pragma unroll
      for (int m = 0; m < 4; ++m) {
        int row = wr * 64 + m * 16 + r;
        int slot = (hi + kc * 4) ^ (row & 7);
        af[m] = *(const short8*)&As[row * 64 + slot * 8];
      }
#pragma unroll
      for (int n = 0; n < 4; ++n) {
        int row = wc * 64 + n * 16 + r;
        int slot = (hi + kc * 4) ^ (row & 7);
        bfr[n] = *(const short8*)&Bs[row * 64 + slot * 8];
      }
#pragma unroll
      for (int m = 0; m < 4; ++m)
#pragma unroll
        for (int n = 0; n < 4; ++n)
          acc[m][n] = __builtin_amdgcn_mfma_f32_16x16x32_bf16(af[m], bfr[n], acc[m][n], 0, 0, 0);
    }
    __syncthreads();
  }

#pragma unroll
  for (int m = 0; m < 4; ++m)
#pragma unroll
    for (int n = 0; n < 4; ++n)
#pragma unroll
      for (int r2 = 0; r2 < 4; ++r2) {
        int grow = bm * 128 + wr * 64 + m * 16 + hi * 4 + r2;
        int gcol = bn * 128 + wc * 64 + n * 16 + r;
        if (OUTF32)
          ((float*)Cv)[(size_t)grow * N + gcol] = acc[m][n][r2];
        else
          ((u16*)Cv)[(size_t)grow * N + gcol] = f2b(acc[m][n][r2]);
      }
}

// ---------------- per-head RMSNorm + RoPE for Q and K ----------------
__global__ __launch_bounds__(256) void rmsnorm_rope(const u16* __restrict__ qkv, const float* __restrict__ fc,
                                                    const float* __restrict__ qw, const float* __restrict__ kw,
                                                    u16* __restrict__ qr, u16* __restrict__ kr) {
  const int tid = threadIdx.x, wave = tid >> 6, lane = tid & 63;
  const int rowid = blockIdx.x * 4 + wave;
  const int token = rowid / 24;
  const int hh = rowid % 24;
  const int b = token >> 11, s = token & 2047;
  const bool isq = hh < 16;
  const int off = isq ? hh * 128 : 2048 + (hh - 16) * 128;
  const u16* src = qkv + (size_t)token * 4096 + off + lane * 2;
  unsigned pv = *(const unsigned*)src;
  float t0 = b2f((u16)(pv & 0xffffu));
  float t1 = b2f((u16)(pv >> 16));
  float ss = t0 * t0 + t1 * t1;
#pragma unroll
  for (int mm = 1; mm < 64; mm <<= 1) ss += __shfl_xor(ss, mm, 64);
  float rms = rsqrtf(ss * (1.0f / 128.0f) + 1e-6f);
  const float* nw = isq ? qw : kw;
  t0 *= rms * nw[lane * 2];
  t1 *= rms * nw[lane * 2 + 1];
  float c = fc[(s * 64 + lane) * 2], sn = fc[(s * 64 + lane) * 2 + 1];
  float o0 = t0 * c - t1 * sn;
  float o1 = t0 * sn + t1 * c;
  unsigned ov = (unsigned)f2b(o0) | ((unsigned)f2b(o1) << 16);
  if (isq)
    *(unsigned*)(qr + ((size_t)(b * 16 + hh) * 2048 + s) * 128 + lane * 2) = ov;
  else
    *(unsigned*)(kr + ((size_t)(b * 8 + hh - 16) * 2048 + s) * 128 + lane * 2) = ov;
}

// ---------------- V transpose: qkv v-section -> vt[b][hkv][d][s]; also zeroes attn ctr ----------------
__global__ __launch_bounds__(256) void v_transpose(const u16* __restrict__ qkv, u16* __restrict__ vt,
                                                   int* __restrict__ ctr) {
  if (blockIdx.x == 0 && threadIdx.x == 0) *ctr = 0;  // runs before attn (stream order)
  __shared__ __align__(16) u16 tile[64][136];
  const int blk = blockIdx.x;
  const int st = blk & 31, h = (blk >> 5) & 7, b = blk >> 8;
  const int s0 = st * 64, t = threadIdx.x;
#pragma unroll
  for (int p = 0; p < 4; ++p) {
    int row = p * 16 + (t >> 4), c8 = (t & 15) * 8;
    const u16* src = qkv + (size_t)(b * 2048 + s0 + row) * 4096 + 3072 + h * 128 + c8;
    *(short8*)&tile[row][c8] = *(const short8*)src;
  }
  __syncthreads();
  const int d = t >> 1, j0 = (t & 1) * 32;
  u16* dst = vt + ((size_t)(b * 8 + h) * 128 + d) * 2048 + s0 + j0;
#pragma unroll
  for (int j = 0; j < 32; j += 8) {
    short8 v;
#pragma unroll
    for (int u = 0; u < 8; ++u) v[u] = (short)tile[j0 + j + u][d];
    *(short8*)(dst + j) = v;
  }
}

// ---------------- causal flash attention v4: 32x32 MFMA + permlane repack ----------------
// 4 waves x 32 q-rows; KVBLK=64; K/V double-buffered LDS (XOR swizzled); swapped QK^T
// (S[kv][q]) and swapped PV (O[d][q]); P repack fully in-register (cvt_pk + permlane32_swap).
__global__ __launch_bounds__(256, 2) void attn4(const u16* __restrict__ qr, const u16* __restrict__ kr,
                                                const u16* __restrict__ vt, u16* __restrict__ ao,
                                                int* __restrict__ ctr) {
  __shared__ __align__(16) u16 Ks[2][64 * 128];
  __shared__ __align__(16) u16 Vs[2][128 * 64];
  __shared__ int tileno;
  const int tid = threadIdx.x, wave = tid >> 6, lane = tid & 63;
  const int ql = lane & 31, lh = lane >> 5;

  for (;;) {
    if (tid == 0) tileno = atomicAdd(ctr, 1);
    __syncthreads();
    const int n = tileno;
    if (n >= 512) break;
    const int t = 15 - (n >> 5);     // big-tile-first
    const int bh = n & 31;
    const int b = bh >> 4, h = bh & 15, hkv = h >> 1;

    const u16* Q  = qr + (size_t)(b * 16 + h) * S_ * HD;
    const u16* Kg = kr + (size_t)(b * 8 + hkv) * S_ * HD;
    const u16* Vg = vt + (size_t)(b * 8 + hkv) * HD * S_;

    const int q0w = t * 128 + wave * 32;
    const int nsteps = 2 * (t + 1);

    // Q fragments (B-operand of 32x32x16): lane holds Q[q0w+ql][ki*16 + lh*8 .. +8)
    short8 qf[8];
#pragma unroll
    for (int ki = 0; ki < 8; ++ki)
      qf[ki] = *(const short8*)(Q + (size_t)(q0w + ql) * HD + ki * 16 + lh * 8);

    f32x16 o[4];
#pragma unroll
    for (int dt = 0; dt < 4; ++dt) o[dt] = 0.f;
    float m = -1e30f, l = 0.f;

    auto stage = [&](int buf, int kv0) {
#pragma unroll
      for (int inst = 0; inst < 4; ++inst) {
        int p = wave * 4096 + inst * 1024 + lane * 16;   // byte pos in 16KB K tile
        int row = p >> 8;                                // kv row (256B rows)
        int colb = (p & 255) ^ ((row & 7) << 4);         // inverse swizzle on SOURCE
        load_lds16(Kg + (((size_t)(kv0 + row)) << 7) + (colb >> 1),
                   &Ks[buf][(wave * 4096 + inst * 1024) >> 1]);
      }
#pragma unroll
      for (int inst = 0; inst < 4; ++inst) {
        int p = wave * 4096 + inst * 1024 + lane * 16;   // byte pos in 16KB V tile
        int d = p >> 7;                                  // d row (128B rows)
        int colb = (p & 127) ^ ((d & 7) << 4);
        load_lds16(Vg + (size_t)d * S_ + kv0 + (colb >> 1),
                   &Vs[buf][(wave * 4096 + inst * 1024) >> 1]);
      }
    };

    stage(0, 0);
    for (int i = 0; i < nsteps; ++i) {
      const int kv0 = i * 64;
      const u16* kb = Ks[i & 1];
      const u16* vb = Vs[i & 1];
      if (i + 1 < nsteps) {
        stage((i + 1) & 1, kv0 + 64);
        ASM_VMCNT(8);          // current buffers complete; next-tile loads stay in flight
      } else {
        ASM_VMCNT(0);
      }
      __builtin_amdgcn_sched_barrier(0);
      __builtin_amdgcn_s_barrier();
      __builtin_amdgcn_sched_barrier(0);

      if (kv0 < q0w + 32) {    // wave-uniform: not fully masked
        // ---- QK^T (swapped, 32x32x16): sacc[kvt] = S[kv0+kvt*32+rowpat][q0w+ql]
        f32x16 sacc[2];
        sacc[0] = 0.f; sacc[1] = 0.f;
        __builtin_amdgcn_s_setprio(1);
#pragma unroll
        for (int ki = 0; ki < 8; ++ki) {
          const int off = ki * 32 + lh * 16;   // byte col in K row
#pragma unroll
          for (int kvt = 0; kvt < 2; ++kvt) {
            const int row = kvt * 32 + ql;
            short8 kf = *(const short8*)&kb[(row << 7) + ((off ^ ((row & 7) << 4)) >> 1)];
            sacc[kvt] = __builtin_amdgcn_mfma_f32_32x32x16_bf16(kf, qf[ki], sacc[kvt], 0, 0, 0);
          }
        }
        __builtin_amdgcn_s_setprio(0);
        // ---- causal mask (diagonal steps only); kv = kv0+kvt*32+(reg&3)+8*(reg>>2)+4*lh
        const int q = q0w + ql;
        if (kv0 + 64 > q0w) {
#pragma unroll
          for (int kvt = 0; kvt < 2; ++kvt) {
            const int kvb = kv0 + kvt * 32 + 4 * lh;
#pragma unroll
            for (int reg = 0; reg < 16; ++reg) {
              const int kvr = kvb + (reg & 3) + 8 * (reg >> 2);
              sacc[kvt][reg] = (kvr > q) ? -1e30f : sacc[kvt][reg];
            }
          }
        }
        // ---- online softmax: lane holds 32 of the 64 kv for q; partner lane has rest
        float mx = sacc[0][0];
#pragma unroll
        for (int kvt = 0; kvt < 2; ++kvt)
#pragma unroll
          for (int reg = 0; reg < 16; ++reg) mx = fmaxf(mx, sacc[kvt][reg]);
        mx = fmaxf(mx, __shfl_xor(mx, 32, 64));
        if (__any(mx > m + RTHR)) {
          float mn = fmaxf(m, mx);
          float sc = exp2f_fast((m - mn) * CEXP);
          l *= sc;
          m = mn;
#pragma unroll
          for (int dt = 0; dt < 4; ++dt)
#pragma unroll
            for (int reg = 0; reg < 16; ++reg) o[dt][reg] *= sc;
        }
        // ---- exp + pack + permlane repack -> PV B-fragments pf[kc] (kc: kv-16 chunks)
        short8 pf[4];
        const float mc = m * CEXP;
        float ps = 0.f;
#pragma unroll
        for (int kvt = 0; kvt < 2; ++kvt) {
          float p[16];
#pragma unroll
          for (int reg = 0; reg < 16; ++reg) {
            p[reg] = exp2f_fast(__builtin_fmaf(sacc[kvt][reg], CEXP, -mc));
            ps += p[reg];
          }
          // regs: kv(of tile) = (reg&3)+8*(reg>>2)+4*lh
          int A0 = cvtpk(p[0], p[1]),  B0 = cvtpk(p[2], p[3]);
          int C0 = cvtpk(p[4], p[5]),  D0 = cvtpk(p[6], p[7]);
          int A1 = cvtpk(p[8], p[9]),  B1 = cvtpk(p[10], p[11]);
          int C1 = cvtpk(p[12], p[13]), D1 = cvtpk(p[14], p[15]);
          pl32swap(A0, C0);  // lo: A0=kv(0,1) C0=kv(4,5) | hi: A0=kv(8,9) C0=kv(12,13)
          pl32swap(B0, D0);  // lo: B0=kv(2,3) D0=kv(6,7) | hi: B0=kv(10,11) D0=kv(14,15)
          pl32swap(A1, C1);
          pl32swap(B1, D1);
          i32x4 w0 = (i32x4){A0, B0, C0, D0};
          i32x4 w1 = (i32x4){A1, B1, C1, D1};
          pf[kvt * 2]     = *(short8*)&w0;   // kv [kvt*32, +16)
          pf[kvt * 2 + 1] = *(short8*)&w1;   // kv [kvt*32+16, +16)
        }
        l += ps;
        // ---- PV (swapped, 32x32x16): o[dt] = O[dt*32+rowpat][q0w+ql]
        __builtin_amdgcn_s_setprio(1);
#pragma unroll
        for (int kc = 0; kc < 4; ++kc) {
          const int off = kc * 32 + lh * 16;   // byte col in V row (kv dim)
#pragma unroll
          for (int dt = 0; dt < 4; ++dt) {
            const int d = dt * 32 + ql;
            short8 vf = *(const short8*)&vb[(d << 6) + ((off ^ ((d & 7) << 4)) >> 1)];
            o[dt] = __builtin_amdgcn_mfma_f32_32x32x16_bf16(vf, pf[kc], o[dt], 0, 0, 0);
          }
        }
        __builtin_amdgcn_s_setprio(0);
      }
      __builtin_amdgcn_sched_barrier(0);
      __builtin_amdgcn_s_barrier();   // buffer consumed; next iter may overwrite
      __builtin_amdgcn_sched_barrier(0);
    }

    // ---- epilogue: merge partner-l, normalize, store O[d][q]-layout to ao[q][d]
    l += __shfl_xor(l, 32, 64);
    const float inv = 1.0f / l;
    const size_t rowoff = ((size_t)(b * 2048 + q0w + ql)) * 2048 + h * 128;
#pragma unroll
    for (int dt = 0; dt < 4; ++dt)
#pragma unroll
      for (int g = 0; g < 4; ++g) {
        const int d0 = dt * 32 + 8 * g + 4 * lh;
        int w0 = cvtpk(o[dt][4 * g] * inv, o[dt][4 * g + 1] * inv);
        int w1 = cvtpk(o[dt][4 * g + 2] * inv, o[dt][4 * g + 3] * inv);
        i32x2 pk = (i32x2){w0, w1};
        *(i32x2*)((u16*)ao + rowoff + d0) = pk;
      }
    __syncthreads();  // all waves done with LDS before next tile's stage(0)
  }
}

extern "C" void kernel_launch(void* const* d_in, const int* in_sizes, int n_in,
                              void* d_out, int out_size, void* d_ws, size_t ws_size,
                              hipStream_t stream) {
  const float* x = (const float*)d_in[0];
  const float* fc = (const float*)d_in[1];
  const float* wq = (const float*)d_in[2];
  const float* wk = (const float*)d_in[3];
  const float* wv = (const float*)d_in[4];
  const float* wo = (const float*)d_in[5];
  const float* qw = (const float*)d_in[6];
  const float* kw = (const float*)d_in[7];
  float* out = (float*)d_out;
  char* ws = (char*)d_ws;

  u16* xb    = (u16*)(ws);                 // [4096][2048] bf16   16 MB
  u16* wqkvb = (u16*)(ws + 16777216);      // [4096][2048] bf16   16 MB
  u16* wob   = (u16*)(ws + 33554432);      // [2048][2048] bf16    8 MB
  u16* qkv   = (u16*)(ws + 41943040);      // [4096][4096] bf16   32 MB
  u16* qrope = (u16*)(ws + 75497472);      // [2][16][2048][128]  16 MB
  u16* krope = (u16*)(ws + 92274688);      // [2][8][2048][128]    8 MB
  u16* vtb   = (u16*)(ws + 100663296);     // [2][8][128][2048]    8 MB
  u16* ao    = (u16*)(ws + 109051904);     // [4096][2048] bf16   16 MB
  int* ctr   = (int*)qkv;                  // dead after v_transpose; zeroed there

  cvt_all<<<20480, 256, 0, stream>>>(x, wq, wk, wv, wo, xb, wqkvb, wob);

  dim3 g1(32, 32);
  gemm_bt<0><<<g1, 256, 0, stream>>>(xb, wqkvb, (void*)qkv, 4096, 4096, 2048);

  rmsnorm_rope<<<24576, 256, 0, stream>>>(qkv, fc, qw, kw, qrope, krope);
  v_transpose<<<512, 256, 0, stream>>>(qkv, vtb, ctr);

  attn4<<<448, 256, 0, stream>>>(qrope, krope, vtb, ao, ctr);

  dim3 g2(32, 16);
  gemm_bt<1><<<g2, 256, 0, stream>>>(ao, wob, (void*)out, 4096, 2048, 2048);
}

// Round 5
// 227.479 us; speedup vs baseline: 2.9511x; 1.0690x over previous
//
#include <hip/hip_runtime.h>

#define B_ 2
#define S_ 2048
#define D_ 2048
#define NH 16
#define NKV 8
#define HD 128
#define SCALE 0.08838834764831845f
#define CEXP 0.1275255f          // SCALE * log2(e)
#define RTHR 62.733f             // 8 / CEXP  (defer-max threshold, p <= 2^8)

typedef unsigned short u16;
typedef __attribute__((ext_vector_type(8))) short short8;
typedef __attribute__((ext_vector_type(4))) float f32x4;
typedef __attribute__((ext_vector_type(16))) float f32x16;
typedef __attribute__((ext_vector_type(4))) int i32x4;
typedef __attribute__((ext_vector_type(2))) int i32x2;

#define ASM_VMCNT(N) asm volatile("s_waitcnt vmcnt(" #N ")" ::: "memory")

__device__ __forceinline__ u16 f2b(float f) {
  union { float f; unsigned u; } c; c.f = f;
  unsigned u = c.u;
  return (u16)((u + 0x7fffu + ((u >> 16) & 1u)) >> 16);
}
__device__ __forceinline__ float b2f(u16 h) {
  union { unsigned u; float f; } c; c.u = ((unsigned)h) << 16;
  return c.f;
}
__device__ __forceinline__ float exp2f_fast(float x) {
  float r; asm("v_exp_f32 %0, %1" : "=v"(r) : "v"(x)); return r;
}
__device__ __forceinline__ int cvtpk(float a, float b) {  // low16=bf16(a), high16=bf16(b)
  int r; asm("v_cvt_pk_bf16_f32 %0, %1, %2" : "=v"(r) : "v"(a), "v"(b)); return r;
}
// swap: a.hi32lanes <-> b.lo32lanes (both regs updated)
__device__ __forceinline__ void pl32swap(int& a, int& b) {
  asm volatile("v_permlane32_swap_b32 %0, %1" : "+v"(a), "+v"(b));
}

__device__ __forceinline__ void load_lds16(const u16* g, u16* l) {
  __builtin_amdgcn_global_load_lds(
      (const __attribute__((address_space(1))) unsigned int*)g,
      (__attribute__((address_space(3))) unsigned int*)l, 16, 0, 0);
}

// ---------------- fused f32 -> bf16 conversion (all 5 tensors, 1 launch) ----------------
__global__ __launch_bounds__(256) void cvt_all(const float* __restrict__ x,
                                               const float* __restrict__ wq,
                                               const float* __restrict__ wk,
                                               const float* __restrict__ wv,
                                               const float* __restrict__ wo,
                                               u16* __restrict__ xb,
                                               u16* __restrict__ wqkvb,
                                               u16* __restrict__ wob) {
  const int blk = blockIdx.x;
  const float* src; u16* dst; int base;
  if (blk < 8192)       { src = x;  dst = xb;                  base = blk; }
  else if (blk < 12288) { src = wq; dst = wqkvb;               base = blk - 8192; }
  else if (blk < 14336) { src = wk; dst = wqkvb + 2048 * 2048; base = blk - 12288; }
  else if (blk < 16384) { src = wv; dst = wqkvb + 3072 * 2048; base = blk - 14336; }
  else                  { src = wo; dst = wob;                 base = blk - 16384; }
  int i = base * 256 + threadIdx.x;
  float4 v = ((const float4*)src)[i];
  u16 o0 = f2b(v.x), o1 = f2b(v.y), o2 = f2b(v.z), o3 = f2b(v.w);
  unsigned long long packed = (unsigned long long)o0 | ((unsigned long long)o1 << 16) |
                              ((unsigned long long)o2 << 32) | ((unsigned long long)o3 << 48);
  ((unsigned long long*)dst)[i] = packed;
}

// ---------------- GEMM v2: C[M,N] = A[M,K] * B[N,K]^T (bf16 in, f32 acc) ----------------
// 128x128 tile, BK=64, 4 waves (2x2), XOR-swizzled dbuf LDS, counted vmcnt (attn4 pattern),
// bijective XCD-chunk block swizzle (grid must be %8==0).
template<int OUTF32>
__global__ __launch_bounds__(256, 2) void gemm_bt2(const u16* __restrict__ A, const u16* __restrict__ Bm,
                                                   void* __restrict__ Cv, int M, int N, int K, int nbn) {
  __shared__ __align__(16) u16 As[2][128 * 64];
  __shared__ __align__(16) u16 Bs[2][128 * 64];
  const int tid = threadIdx.x;
  const int wave = tid >> 6, lane = tid & 63;
  const int nwg = gridDim.x, cpx = nwg >> 3;
  const int L = (blockIdx.x & 7) * cpx + (blockIdx.x >> 3);
  const int bm = L / nbn, bn = L % nbn;
  const int wr = wave >> 1, wc = wave & 1;
  const int r = lane & 15, hi = lane >> 4;

  f32x4 acc[4][4];
#pragma unroll
  for (int m = 0; m < 4; ++m)
#pragma unroll
    for (int n = 0; n < 4; ++n) acc[m][n] = (f32x4){0.f, 0.f, 0.f, 0.f};

  const int gslot = (lane & 7) ^ (lane >> 3);  // inverse swizzle on global SOURCE
  const int srow = lane >> 3;

  auto stage = [&](int buf, int k0) {
#pragma unroll
    for (int jj = 0; jj < 4; ++jj) {
      int j = wave * 4 + jj;
      int row = j * 8 + srow;
      load_lds16(A + (size_t)(bm * 128 + row) * K + k0 + gslot * 8, &As[buf][j * 512]);
      load_lds16(Bm + (size_t)(bn * 128 + row) * K + k0 + gslot * 8, &Bs[buf][j * 512]);
    }
  };

  const int nk = K >> 6;
  stage(0, 0);
  for (int kt = 0; kt < nk; ++kt) {
    if (kt + 1 < nk) {
      stage((kt + 1) & 1, (kt + 1) << 6);
      ASM_VMCNT(8);          // current tile's 8 loads landed; next tile's stay in flight
    } else {
      ASM_VMCNT(0);
    }
    __builtin_amdgcn_sched_barrier(0);
    __builtin_amdgcn_s_barrier();
    __builtin_amdgcn_sched_barrier(0);
    const u16* as = As[kt & 1];
    const u16* bs = Bs[kt & 1];
#pragma unroll
    for (int kc = 0; kc < 2; ++kc) {
      short8 af[4], bfr[4];
#pragma unroll
      for (int m = 0; m < 4; ++m) {
        int row = wr * 64 + m * 16 + r;
        int slot = (hi + kc * 4) ^ (row & 7);
        af[m] = *(const short8*)&as[row * 64 + slot * 8];
      }
#pragma unroll
      for (int n = 0; n < 4; ++n) {
        int row = wc * 64 + n * 16 + r;
        int slot = (hi + kc * 4) ^ (row & 7);
        bfr[n] = *(const short8*)&bs[row * 64 + slot * 8];
      }
#pragma unroll
      for (int m = 0; m < 4; ++m)
#pragma unroll
        for (int n = 0; n < 4; ++n)
          acc[m][n] = __builtin_amdgcn_mfma_f32_16x16x32_bf16(af[m], bfr[n], acc[m][n], 0, 0, 0);
    }
    __builtin_amdgcn_sched_barrier(0);
    __builtin_amdgcn_s_barrier();   // reads done before next iter's stage overwrites
    __builtin_amdgcn_sched_barrier(0);
  }

#pragma unroll
  for (int m = 0; m < 4; ++m)
#pragma unroll
    for (int n = 0; n < 4; ++n)
#pragma unroll
      for (int r2 = 0; r2 < 4; ++r2) {
        int grow = bm * 128 + wr * 64 + m * 16 + hi * 4 + r2;
        int gcol = bn * 128 + wc * 64 + n * 16 + r;
        if (OUTF32)
          ((float*)Cv)[(size_t)grow * N + gcol] = acc[m][n][r2];
        else
          ((u16*)Cv)[(size_t)grow * N + gcol] = f2b(acc[m][n][r2]);
      }
}

// ---------------- per-head RMSNorm + RoPE for Q and K ----------------
__global__ __launch_bounds__(256) void rmsnorm_rope(const u16* __restrict__ qkv, const float* __restrict__ fc,
                                                    const float* __restrict__ qw, const float* __restrict__ kw,
                                                    u16* __restrict__ qr, u16* __restrict__ kr) {
  const int tid = threadIdx.x, wave = tid >> 6, lane = tid & 63;
  const int rowid = blockIdx.x * 4 + wave;
  const int token = rowid / 24;
  const int hh = rowid % 24;
  const int b = token >> 11, s = token & 2047;
  const bool isq = hh < 16;
  const int off = isq ? hh * 128 : 2048 + (hh - 16) * 128;
  const u16* src = qkv + (size_t)token * 4096 + off + lane * 2;
  unsigned pv = *(const unsigned*)src;
  float t0 = b2f((u16)(pv & 0xffffu));
  float t1 = b2f((u16)(pv >> 16));
  float ss = t0 * t0 + t1 * t1;
#pragma unroll
  for (int mm = 1; mm < 64; mm <<= 1) ss += __shfl_xor(ss, mm, 64);
  float rms = rsqrtf(ss * (1.0f / 128.0f) + 1e-6f);
  const float* nw = isq ? qw : kw;
  t0 *= rms * nw[lane * 2];
  t1 *= rms * nw[lane * 2 + 1];
  float c = fc[(s * 64 + lane) * 2], sn = fc[(s * 64 + lane) * 2 + 1];
  float o0 = t0 * c - t1 * sn;
  float o1 = t0 * sn + t1 * c;
  unsigned ov = (unsigned)f2b(o0) | ((unsigned)f2b(o1) << 16);
  if (isq)
    *(unsigned*)(qr + ((size_t)(b * 16 + hh) * 2048 + s) * 128 + lane * 2) = ov;
  else
    *(unsigned*)(kr + ((size_t)(b * 8 + hh - 16) * 2048 + s) * 128 + lane * 2) = ov;
}

// ---------------- V transpose: qkv v-section -> vt[b][hkv][d][s]; also zeroes attn ctr ----------------
__global__ __launch_bounds__(256) void v_transpose(const u16* __restrict__ qkv, u16* __restrict__ vt,
                                                   int* __restrict__ ctr) {
  if (blockIdx.x == 0 && threadIdx.x == 0) *ctr = 0;  // runs before attn (stream order)
  __shared__ __align__(16) u16 tile[64][136];
  const int blk = blockIdx.x;
  const int st = blk & 31, h = (blk >> 5) & 7, b = blk >> 8;
  const int s0 = st * 64, t = threadIdx.x;
#pragma unroll
  for (int p = 0; p < 4; ++p) {
    int row = p * 16 + (t >> 4), c8 = (t & 15) * 8;
    const u16* src = qkv + (size_t)(b * 2048 + s0 + row) * 4096 + 3072 + h * 128 + c8;
    *(short8*)&tile[row][c8] = *(const short8*)src;
  }
  __syncthreads();
  const int d = t >> 1, j0 = (t & 1) * 32;
  u16* dst = vt + ((size_t)(b * 8 + h) * 128 + d) * 2048 + s0 + j0;
#pragma unroll
  for (int j = 0; j < 32; j += 8) {
    short8 v;
#pragma unroll
    for (int u = 0; u < 8; ++u) v[u] = (short)tile[j0 + j + u][d];
    *(short8*)(dst + j) = v;
  }
}

// ---------------- causal flash attention v4: 32x32 MFMA + permlane repack ----------------
__global__ __launch_bounds__(256, 2) void attn4(const u16* __restrict__ qr, const u16* __restrict__ kr,
                                                const u16* __restrict__ vt, u16* __restrict__ ao,
                                                int* __restrict__ ctr) {
  __shared__ __align__(16) u16 Ks[2][64 * 128];
  __shared__ __align__(16) u16 Vs[2][128 * 64];
  __shared__ int tileno;
  const int tid = threadIdx.x, wave = tid >> 6, lane = tid & 63;
  const int ql = lane & 31, lh = lane >> 5;

  for (;;) {
    if (tid == 0) tileno = atomicAdd(ctr, 1);
    __syncthreads();
    const int n = tileno;
    if (n >= 512) break;
    const int t = 15 - (n >> 5);     // big-tile-first
    const int bh = n & 31;
    const int b = bh >> 4, h = bh & 15, hkv = h >> 1;

    const u16* Q  = qr + (size_t)(b * 16 + h) * S_ * HD;
    const u16* Kg = kr + (size_t)(b * 8 + hkv) * S_ * HD;
    const u16* Vg = vt + (size_t)(b * 8 + hkv) * HD * S_;

    const int q0w = t * 128 + wave * 32;
    const int nsteps = 2 * (t + 1);

    short8 qf[8];
#pragma unroll
    for (int ki = 0; ki < 8; ++ki)
      qf[ki] = *(const short8*)(Q + (size_t)(q0w + ql) * HD + ki * 16 + lh * 8);

    f32x16 o[4];
#pragma unroll
    for (int dt = 0; dt < 4; ++dt) o[dt] = 0.f;
    float m = -1e30f, l = 0.f;

    auto stage = [&](int buf, int kv0) {
#pragma unroll
      for (int inst = 0; inst < 4; ++inst) {
        int p = wave * 4096 + inst * 1024 + lane * 16;   // byte pos in 16KB K tile
        int row = p >> 8;                                // kv row (256B rows)
        int colb = (p & 255) ^ ((row & 7) << 4);         // inverse swizzle on SOURCE
        load_lds16(Kg + (((size_t)(kv0 + row)) << 7) + (colb >> 1),
                   &Ks[buf][(wave * 4096 + inst * 1024) >> 1]);
      }
#pragma unroll
      for (int inst = 0; inst < 4; ++inst) {
        int p = wave * 4096 + inst * 1024 + lane * 16;   // byte pos in 16KB V tile
        int d = p >> 7;                                  // d row (128B rows)
        int colb = (p & 127) ^ ((d & 7) << 4);
        load_lds16(Vg + (size_t)d * S_ + kv0 + (colb >> 1),
                   &Vs[buf][(wave * 4096 + inst * 1024) >> 1]);
      }
    };

    stage(0, 0);
    for (int i = 0; i < nsteps; ++i) {
      const int kv0 = i * 64;
      const u16* kb = Ks[i & 1];
      const u16* vb = Vs[i & 1];
      if (i + 1 < nsteps) {
        stage((i + 1) & 1, kv0 + 64);
        ASM_VMCNT(8);
      } else {
        ASM_VMCNT(0);
      }
      __builtin_amdgcn_sched_barrier(0);
      __builtin_amdgcn_s_barrier();
      __builtin_amdgcn_sched_barrier(0);

      if (kv0 < q0w + 32) {
        f32x16 sacc[2];
        sacc[0] = 0.f; sacc[1] = 0.f;
        __builtin_amdgcn_s_setprio(1);
#pragma unroll
        for (int ki = 0; ki < 8; ++ki) {
          const int off = ki * 32 + lh * 16;
#pragma unroll
          for (int kvt = 0; kvt < 2; ++kvt) {
            const int row = kvt * 32 + ql;
            short8 kf = *(const short8*)&kb[(row << 7) + ((off ^ ((row & 7) << 4)) >> 1)];
            sacc[kvt] = __builtin_amdgcn_mfma_f32_32x32x16_bf16(kf, qf[ki], sacc[kvt], 0, 0, 0);
          }
        }
        __builtin_amdgcn_s_setprio(0);
        const int q = q0w + ql;
        if (kv0 + 64 > q0w) {
#pragma unroll
          for (int kvt = 0; kvt < 2; ++kvt) {
            const int kvb = kv0 + kvt * 32 + 4 * lh;
#pragma unroll
            for (int reg = 0; reg < 16; ++reg) {
              const int kvr = kvb + (reg & 3) + 8 * (reg >> 2);
              sacc[kvt][reg] = (kvr > q) ? -1e30f : sacc[kvt][reg];
            }
          }
        }
        float mx = sacc[0][0];
#pragma unroll
        for (int kvt = 0; kvt < 2; ++kvt)
#pragma unroll
          for (int reg = 0; reg < 16; ++reg) mx = fmaxf(mx, sacc[kvt][reg]);
        mx = fmaxf(mx, __shfl_xor(mx, 32, 64));
        if (__any(mx > m + RTHR)) {
          float mn = fmaxf(m, mx);
          float sc = exp2f_fast((m - mn) * CEXP);
          l *= sc;
          m = mn;
#pragma unroll
          for (int dt = 0; dt < 4; ++dt)
#pragma unroll
            for (int reg = 0; reg < 16; ++reg) o[dt][reg] *= sc;
        }
        short8 pf[4];
        const float mc = m * CEXP;
        float ps = 0.f;
#pragma unroll
        for (int kvt = 0; kvt < 2; ++kvt) {
          float p[16];
#pragma unroll
          for (int reg = 0; reg < 16; ++reg) {
            p[reg] = exp2f_fast(__builtin_fmaf(sacc[kvt][reg], CEXP, -mc));
            ps += p[reg];
          }
          int A0 = cvtpk(p[0], p[1]),  B0 = cvtpk(p[2], p[3]);
          int C0 = cvtpk(p[4], p[5]),  D0 = cvtpk(p[6], p[7]);
          int A1 = cvtpk(p[8], p[9]),  B1 = cvtpk(p[10], p[11]);
          int C1 = cvtpk(p[12], p[13]), D1 = cvtpk(p[14], p[15]);
          pl32swap(A0, C0);
          pl32swap(B0, D0);
          pl32swap(A1, C1);
          pl32swap(B1, D1);
          i32x4 w0 = (i32x4){A0, B0, C0, D0};
          i32x4 w1 = (i32x4){A1, B1, C1, D1};
          pf[kvt * 2]     = *(short8*)&w0;
          pf[kvt * 2 + 1] = *(short8*)&w1;
        }
        l += ps;
        __builtin_amdgcn_s_setprio(1);
#pragma unroll
        for (int kc = 0; kc < 4; ++kc) {
          const int off = kc * 32 + lh * 16;
#pragma unroll
          for (int dt = 0; dt < 4; ++dt) {
            const int d = dt * 32 + ql;
            short8 vf = *(const short8*)&vb[(d << 6) + ((off ^ ((d & 7) << 4)) >> 1)];
            o[dt] = __builtin_amdgcn_mfma_f32_32x32x16_bf16(vf, pf[kc], o[dt], 0, 0, 0);
          }
        }
        __builtin_amdgcn_s_setprio(0);
      }
      __builtin_amdgcn_sched_barrier(0);
      __builtin_amdgcn_s_barrier();
      __builtin_amdgcn_sched_barrier(0);
    }

    l += __shfl_xor(l, 32, 64);
    const float inv = 1.0f / l;
    const size_t rowoff = ((size_t)(b * 2048 + q0w + ql)) * 2048 + h * 128;
#pragma unroll
    for (int dt = 0; dt < 4; ++dt)
#pragma unroll
      for (int g = 0; g < 4; ++g) {
        const int d0 = dt * 32 + 8 * g + 4 * lh;
        int w0 = cvtpk(o[dt][4 * g] * inv, o[dt][4 * g + 1] * inv);
        int w1 = cvtpk(o[dt][4 * g + 2] * inv, o[dt][4 * g + 3] * inv);
        i32x2 pk = (i32x2){w0, w1};
        *(i32x2*)((u16*)ao + rowoff + d0) = pk;
      }
    __syncthreads();
  }
}

extern "C" void kernel_launch(void* const* d_in, const int* in_sizes, int n_in,
                              void* d_out, int out_size, void* d_ws, size_t ws_size,
                              hipStream_t stream) {
  const float* x = (const float*)d_in[0];
  const float* fc = (const float*)d_in[1];
  const float* wq = (const float*)d_in[2];
  const float* wk = (const float*)d_in[3];
  const float* wv = (const float*)d_in[4];
  const float* wo = (const float*)d_in[5];
  const float* qw = (const float*)d_in[6];
  const float* kw = (const float*)d_in[7];
  float* out = (float*)d_out;
  char* ws = (char*)d_ws;

  u16* xb    = (u16*)(ws);                 // [4096][2048] bf16   16 MB
  u16* wqkvb = (u16*)(ws + 16777216);      // [4096][2048] bf16   16 MB
  u16* wob   = (u16*)(ws + 33554432);      // [2048][2048] bf16    8 MB
  u16* qkv   = (u16*)(ws + 41943040);      // [4096][4096] bf16   32 MB
  u16* qrope = (u16*)(ws + 75497472);      // [2][16][2048][128]  16 MB
  u16* krope = (u16*)(ws + 92274688);      // [2][8][2048][128]    8 MB
  u16* vtb   = (u16*)(ws + 100663296);     // [2][8][128][2048]    8 MB
  u16* ao    = (u16*)(ws + 109051904);     // [4096][2048] bf16   16 MB
  int* ctr   = (int*)qkv;                  // dead after v_transpose; zeroed there

  cvt_all<<<20480, 256, 0, stream>>>(x, wq, wk, wv, wo, xb, wqkvb, wob);

  gemm_bt2<0><<<1024, 256, 0, stream>>>(xb, wqkvb, (void*)qkv, 4096, 4096, 2048, 32);

  rmsnorm_rope<<<24576, 256, 0, stream>>>(qkv, fc, qw, kw, qrope, krope);
  v_transpose<<<512, 256, 0, stream>>>(qkv, vtb, ctr);

  attn4<<<448, 256, 0, stream>>>(qrope, krope, vtb, ao, ctr);

  gemm_bt2<1><<<512, 256, 0, stream>>>(ao, wob, (void*)out, 4096, 2048, 2048, 16);
}

// Round 6
// 224.862 us; speedup vs baseline: 2.9854x; 1.0116x over previous
//
#include <hip/hip_runtime.h>

#define B_ 2
#define S_ 2048
#define D_ 2048
#define NH 16
#define NKV 8
#define HD 128
#define SCALE 0.08838834764831845f
#define CEXP 0.1275255f          // SCALE * log2(e)
#define RTHR 62.733f             // 8 / CEXP  (defer-max threshold, p <= 2^8)

typedef unsigned short u16;
typedef __attribute__((ext_vector_type(8))) short short8;
typedef __attribute__((ext_vector_type(4))) float f32x4;
typedef __attribute__((ext_vector_type(16))) float f32x16;
typedef __attribute__((ext_vector_type(4))) int i32x4;
typedef __attribute__((ext_vector_type(2))) int i32x2;

#define ASM_VMCNT(N) asm volatile("s_waitcnt vmcnt(" #N ")" ::: "memory")

__device__ __forceinline__ u16 f2b(float f) {
  union { float f; unsigned u; } c; c.f = f;
  unsigned u = c.u;
  return (u16)((u + 0x7fffu + ((u >> 16) & 1u)) >> 16);
}
__device__ __forceinline__ float b2f(u16 h) {
  union { unsigned u; float f; } c; c.u = ((unsigned)h) << 16;
  return c.f;
}
__device__ __forceinline__ float exp2f_fast(float x) {
  float r; asm("v_exp_f32 %0, %1" : "=v"(r) : "v"(x)); return r;
}
__device__ __forceinline__ int cvtpk(float a, float b) {  // low16=bf16(a), high16=bf16(b)
  int r; asm("v_cvt_pk_bf16_f32 %0, %1, %2" : "=v"(r) : "v"(a), "v"(b)); return r;
}
// swap: a.hi32lanes <-> b.lo32lanes (both regs updated)
__device__ __forceinline__ void pl32swap(int& a, int& b) {
  asm volatile("v_permlane32_swap_b32 %0, %1" : "+v"(a), "+v"(b));
}

__device__ __forceinline__ void load_lds16(const u16* g, u16* l) {
  __builtin_amdgcn_global_load_lds(
      (const __attribute__((address_space(1))) unsigned int*)g,
      (__attribute__((address_space(3))) unsigned int*)l, 16, 0, 0);
}

// ---------------- fused f32 -> bf16 conversion (all 5 tensors, 1 launch) ----------------
__global__ __launch_bounds__(256) void cvt_all(const float* __restrict__ x,
                                               const float* __restrict__ wq,
                                               const float* __restrict__ wk,
                                               const float* __restrict__ wv,
                                               const float* __restrict__ wo,
                                               u16* __restrict__ xb,
                                               u16* __restrict__ wqkvb,
                                               u16* __restrict__ wob) {
  const int blk = blockIdx.x;
  const float* src; u16* dst; int base;
  if (blk < 8192)       { src = x;  dst = xb;                  base = blk; }
  else if (blk < 12288) { src = wq; dst = wqkvb;               base = blk - 8192; }
  else if (blk < 14336) { src = wk; dst = wqkvb + 2048 * 2048; base = blk - 12288; }
  else if (blk < 16384) { src = wv; dst = wqkvb + 3072 * 2048; base = blk - 14336; }
  else                  { src = wo; dst = wob;                 base = blk - 16384; }
  int i = base * 256 + threadIdx.x;
  float4 v = ((const float4*)src)[i];
  u16 o0 = f2b(v.x), o1 = f2b(v.y), o2 = f2b(v.z), o3 = f2b(v.w);
  unsigned long long packed = (unsigned long long)o0 | ((unsigned long long)o1 << 16) |
                              ((unsigned long long)o2 << 32) | ((unsigned long long)o3 << 48);
  ((unsigned long long*)dst)[i] = packed;
}

// ---------------- GEMM v2: C[M,N] = A[M,K] * B[N,K]^T (bf16 in, f32 acc) ----------------
// 128x128 tile, BK=64, 4 waves (2x2), XOR-swizzled dbuf LDS, counted vmcnt,
// bijective XCD-chunk block swizzle (grid must be %8==0).
template<int OUTF32>
__global__ __launch_bounds__(256, 2) void gemm_bt2(const u16* __restrict__ A, const u16* __restrict__ Bm,
                                                   void* __restrict__ Cv, int M, int N, int K, int nbn) {
  __shared__ __align__(16) u16 As[2][128 * 64];
  __shared__ __align__(16) u16 Bs[2][128 * 64];
  const int tid = threadIdx.x;
  const int wave = tid >> 6, lane = tid & 63;
  const int nwg = gridDim.x, cpx = nwg >> 3;
  const int L = (blockIdx.x & 7) * cpx + (blockIdx.x >> 3);
  const int bm = L / nbn, bn = L % nbn;
  const int wr = wave >> 1, wc = wave & 1;
  const int r = lane & 15, hi = lane >> 4;

  f32x4 acc[4][4];
#pragma unroll
  for (int m = 0; m < 4; ++m)
#pragma unroll
    for (int n = 0; n < 4; ++n) acc[m][n] = (f32x4){0.f, 0.f, 0.f, 0.f};

  const int gslot = (lane & 7) ^ (lane >> 3);  // inverse swizzle on global SOURCE
  const int srow = lane >> 3;

  auto stage = [&](int buf, int k0) {
#pragma unroll
    for (int jj = 0; jj < 4; ++jj) {
      int j = wave * 4 + jj;
      int row = j * 8 + srow;
      load_lds16(A + (size_t)(bm * 128 + row) * K + k0 + gslot * 8, &As[buf][j * 512]);
      load_lds16(Bm + (size_t)(bn * 128 + row) * K + k0 + gslot * 8, &Bs[buf][j * 512]);
    }
  };

  const int nk = K >> 6;
  stage(0, 0);
  for (int kt = 0; kt < nk; ++kt) {
    if (kt + 1 < nk) {
      stage((kt + 1) & 1, (kt + 1) << 6);
      ASM_VMCNT(8);          // current tile's 8 loads landed; next tile's stay in flight
    } else {
      ASM_VMCNT(0);
    }
    __builtin_amdgcn_sched_barrier(0);
    __builtin_amdgcn_s_barrier();
    __builtin_amdgcn_sched_barrier(0);
    const u16* as = As[kt & 1];
    const u16* bs = Bs[kt & 1];
#pragma unroll
    for (int kc = 0; kc < 2; ++kc) {
      short8 af[4], bfr[4];
#pragma unroll
      for (int m = 0; m < 4; ++m) {
        int row = wr * 64 + m * 16 + r;
        int slot = (hi + kc * 4) ^ (row & 7);
        af[m] = *(const short8*)&as[row * 64 + slot * 8];
      }
#pragma unroll
      for (int n = 0; n < 4; ++n) {
        int row = wc * 64 + n * 16 + r;
        int slot = (hi + kc * 4) ^ (row & 7);
        bfr[n] = *(const short8*)&bs[row * 64 + slot * 8];
      }
#pragma unroll
      for (int m = 0; m < 4; ++m)
#pragma unroll
        for (int n = 0; n < 4; ++n)
          acc[m][n] = __builtin_amdgcn_mfma_f32_16x16x32_bf16(af[m], bfr[n], acc[m][n], 0, 0, 0);
    }
    __builtin_amdgcn_sched_barrier(0);
    __builtin_amdgcn_s_barrier();   // reads done before next iter's stage overwrites
    __builtin_amdgcn_sched_barrier(0);
  }

#pragma unroll
  for (int m = 0; m < 4; ++m)
#pragma unroll
    for (int n = 0; n < 4; ++n)
#pragma unroll
      for (int r2 = 0; r2 < 4; ++r2) {
        int grow = bm * 128 + wr * 64 + m * 16 + hi * 4 + r2;
        int gcol = bn * 128 + wc * 64 + n * 16 + r;
        if (OUTF32)
          ((float*)Cv)[(size_t)grow * N + gcol] = acc[m][n][r2];
        else
          ((u16*)Cv)[(size_t)grow * N + gcol] = f2b(acc[m][n][r2]);
      }
}

// ---------------- per-head RMSNorm + RoPE for Q and K ----------------
__global__ __launch_bounds__(256) void rmsnorm_rope(const u16* __restrict__ qkv, const float* __restrict__ fc,
                                                    const float* __restrict__ qw, const float* __restrict__ kw,
                                                    u16* __restrict__ qr, u16* __restrict__ kr) {
  const int tid = threadIdx.x, wave = tid >> 6, lane = tid & 63;
  const int rowid = blockIdx.x * 4 + wave;
  const int token = rowid / 24;
  const int hh = rowid % 24;
  const int b = token >> 11, s = token & 2047;
  const bool isq = hh < 16;
  const int off = isq ? hh * 128 : 2048 + (hh - 16) * 128;
  const u16* src = qkv + (size_t)token * 4096 + off + lane * 2;
  unsigned pv = *(const unsigned*)src;
  float t0 = b2f((u16)(pv & 0xffffu));
  float t1 = b2f((u16)(pv >> 16));
  float ss = t0 * t0 + t1 * t1;
#pragma unroll
  for (int mm = 1; mm < 64; mm <<= 1) ss += __shfl_xor(ss, mm, 64);
  float rms = rsqrtf(ss * (1.0f / 128.0f) + 1e-6f);
  const float* nw = isq ? qw : kw;
  t0 *= rms * nw[lane * 2];
  t1 *= rms * nw[lane * 2 + 1];
  float c = fc[(s * 64 + lane) * 2], sn = fc[(s * 64 + lane) * 2 + 1];
  float o0 = t0 * c - t1 * sn;
  float o1 = t0 * sn + t1 * c;
  unsigned ov = (unsigned)f2b(o0) | ((unsigned)f2b(o1) << 16);
  if (isq)
    *(unsigned*)(qr + ((size_t)(b * 16 + hh) * 2048 + s) * 128 + lane * 2) = ov;
  else
    *(unsigned*)(kr + ((size_t)(b * 8 + hh - 16) * 2048 + s) * 128 + lane * 2) = ov;
}

// ---------------- V transpose: qkv v-section -> vt[b][hkv][d][s] ----------------
__global__ __launch_bounds__(256) void v_transpose(const u16* __restrict__ qkv, u16* __restrict__ vt) {
  __shared__ __align__(16) u16 tile[64][136];
  const int blk = blockIdx.x;
  const int st = blk & 31, h = (blk >> 5) & 7, b = blk >> 8;
  const int s0 = st * 64, t = threadIdx.x;
#pragma unroll
  for (int p = 0; p < 4; ++p) {
    int row = p * 16 + (t >> 4), c8 = (t & 15) * 8;
    const u16* src = qkv + (size_t)(b * 2048 + s0 + row) * 4096 + 3072 + h * 128 + c8;
    *(short8*)&tile[row][c8] = *(const short8*)src;
  }
  __syncthreads();
  const int d = t >> 1, j0 = (t & 1) * 32;
  u16* dst = vt + ((size_t)(b * 8 + h) * 128 + d) * 2048 + s0 + j0;
#pragma unroll
  for (int j = 0; j < 32; j += 8) {
    short8 v;
#pragma unroll
    for (int u = 0; u < 8; ++u) v[u] = (short)tile[j0 + j + u][d];
    *(short8*)(dst + j) = v;
  }
}

// ---------------- causal flash attention v5: static paired tiles ----------------
// 256 blocks; block (xcd, idx) -> bh = xcd*4 + (idx&3), pair p = idx>>2; runs tiles
// t = 15-p then t = p  => exactly 34 K-steps per block (perfect balance), bh->XCD L2 affinity.
// 4 waves x 32 q-rows; KVBLK=64; dbuf XOR-swizzled LDS; swapped QK^T / PV; permlane repack.
__global__ __launch_bounds__(256, 2) void attn5(const u16* __restrict__ qr, const u16* __restrict__ kr,
                                                const u16* __restrict__ vt, u16* __restrict__ ao) {
  __shared__ __align__(16) u16 Ks[2][64 * 128];
  __shared__ __align__(16) u16 Vs[2][128 * 64];
  const int tid = threadIdx.x, wave = tid >> 6, lane = tid & 63;
  const int ql = lane & 31, lh = lane >> 5;

  const int xcd = blockIdx.x & 7, idx = blockIdx.x >> 3;
  const int bh = xcd * 4 + (idx & 3);
  const int p = idx >> 2;
  const int b = bh >> 4, h = bh & 15, hkv = h >> 1;

  const u16* Q  = qr + (size_t)(b * 16 + h) * S_ * HD;
  const u16* Kg = kr + (size_t)(b * 8 + hkv) * S_ * HD;
  const u16* Vg = vt + (size_t)(b * 8 + hkv) * HD * S_;

  auto stage = [&](int buf, int kv0) {
#pragma unroll
    for (int inst = 0; inst < 4; ++inst) {
      int pp = wave * 4096 + inst * 1024 + lane * 16;  // byte pos in 16KB K tile
      int row = pp >> 8;                               // kv row (256B rows)
      int colb = (pp & 255) ^ ((row & 7) << 4);        // inverse swizzle on SOURCE
      load_lds16(Kg + (((size_t)(kv0 + row)) << 7) + (colb >> 1),
                 &Ks[buf][(wave * 4096 + inst * 1024) >> 1]);
    }
#pragma unroll
    for (int inst = 0; inst < 4; ++inst) {
      int pp = wave * 4096 + inst * 1024 + lane * 16;  // byte pos in 16KB V tile
      int d = pp >> 7;                                 // d row (128B rows)
      int colb = (pp & 127) ^ ((d & 7) << 4);
      load_lds16(Vg + (size_t)d * S_ + kv0 + (colb >> 1),
                 &Vs[buf][(wave * 4096 + inst * 1024) >> 1]);
    }
  };

#pragma unroll 1
  for (int half = 0; half < 2; ++half) {
    const int t = half ? p : 15 - p;
    const int q0w = t * 128 + wave * 32;
    const int nsteps = 2 * (t + 1);

    short8 qf[8];
#pragma unroll
    for (int ki = 0; ki < 8; ++ki)
      qf[ki] = *(const short8*)(Q + (size_t)(q0w + ql) * HD + ki * 16 + lh * 8);

    f32x16 o[4];
#pragma unroll
    for (int dt = 0; dt < 4; ++dt) o[dt] = 0.f;
    float m = -1e30f, l = 0.f;

    stage(0, 0);
    for (int i = 0; i < nsteps; ++i) {
      const int kv0 = i * 64;
      const u16* kb = Ks[i & 1];
      const u16* vb = Vs[i & 1];
      if (i + 1 < nsteps) {
        stage((i + 1) & 1, kv0 + 64);
        ASM_VMCNT(8);
      } else {
        ASM_VMCNT(0);
      }
      __builtin_amdgcn_sched_barrier(0);
      __builtin_amdgcn_s_barrier();
      __builtin_amdgcn_sched_barrier(0);

      if (kv0 < q0w + 32) {
        f32x16 sacc[2];
        sacc[0] = 0.f; sacc[1] = 0.f;
        __builtin_amdgcn_s_setprio(1);
#pragma unroll
        for (int ki = 0; ki < 8; ++ki) {
          const int off = ki * 32 + lh * 16;
#pragma unroll
          for (int kvt = 0; kvt < 2; ++kvt) {
            const int row = kvt * 32 + ql;
            short8 kf = *(const short8*)&kb[(row << 7) + ((off ^ ((row & 7) << 4)) >> 1)];
            sacc[kvt] = __builtin_amdgcn_mfma_f32_32x32x16_bf16(kf, qf[ki], sacc[kvt], 0, 0, 0);
          }
        }
        __builtin_amdgcn_s_setprio(0);
        const int q = q0w + ql;
        if (kv0 + 64 > q0w) {
#pragma unroll
          for (int kvt = 0; kvt < 2; ++kvt) {
            const int kvb = kv0 + kvt * 32 + 4 * lh;
#pragma unroll
            for (int reg = 0; reg < 16; ++reg) {
              const int kvr = kvb + (reg & 3) + 8 * (reg >> 2);
              sacc[kvt][reg] = (kvr > q) ? -1e30f : sacc[kvt][reg];
            }
          }
        }
        float mx = sacc[0][0];
#pragma unroll
        for (int kvt = 0; kvt < 2; ++kvt)
#pragma unroll
          for (int reg = 0; reg < 16; ++reg) mx = fmaxf(mx, sacc[kvt][reg]);
        mx = fmaxf(mx, __shfl_xor(mx, 32, 64));
        if (__any(mx > m + RTHR)) {
          float mn = fmaxf(m, mx);
          float sc = exp2f_fast((m - mn) * CEXP);
          l *= sc;
          m = mn;
#pragma unroll
          for (int dt = 0; dt < 4; ++dt)
#pragma unroll
            for (int reg = 0; reg < 16; ++reg) o[dt][reg] *= sc;
        }
        short8 pf[4];
        const float mc = m * CEXP;
        float ps = 0.f;
#pragma unroll
        for (int kvt = 0; kvt < 2; ++kvt) {
          float pv[16];
#pragma unroll
          for (int reg = 0; reg < 16; ++reg) {
            pv[reg] = exp2f_fast(__builtin_fmaf(sacc[kvt][reg], CEXP, -mc));
            ps += pv[reg];
          }
          int A0 = cvtpk(pv[0], pv[1]),  B0 = cvtpk(pv[2], pv[3]);
          int C0 = cvtpk(pv[4], pv[5]),  D0 = cvtpk(pv[6], pv[7]);
          int A1 = cvtpk(pv[8], pv[9]),  B1 = cvtpk(pv[10], pv[11]);
          int C1 = cvtpk(pv[12], pv[13]), D1 = cvtpk(pv[14], pv[15]);
          pl32swap(A0, C0);
          pl32swap(B0, D0);
          pl32swap(A1, C1);
          pl32swap(B1, D1);
          i32x4 w0 = (i32x4){A0, B0, C0, D0};
          i32x4 w1 = (i32x4){A1, B1, C1, D1};
          pf[kvt * 2]     = *(short8*)&w0;
          pf[kvt * 2 + 1] = *(short8*)&w1;
        }
        l += ps;
        __builtin_amdgcn_s_setprio(1);
#pragma unroll
        for (int kc = 0; kc < 4; ++kc) {
          const int off = kc * 32 + lh * 16;
#pragma unroll
          for (int dt = 0; dt < 4; ++dt) {
            const int d = dt * 32 + ql;
            short8 vf = *(const short8*)&vb[(d << 6) + ((off ^ ((d & 7) << 4)) >> 1)];
            o[dt] = __builtin_amdgcn_mfma_f32_32x32x16_bf16(vf, pf[kc], o[dt], 0, 0, 0);
          }
        }
        __builtin_amdgcn_s_setprio(0);
      }
      __builtin_amdgcn_sched_barrier(0);
      __builtin_amdgcn_s_barrier();
      __builtin_amdgcn_sched_barrier(0);
    }

    l += __shfl_xor(l, 32, 64);
    const float inv = 1.0f / l;
    const size_t rowoff = ((size_t)(b * 2048 + q0w + ql)) * 2048 + h * 128;
#pragma unroll
    for (int dt = 0; dt < 4; ++dt)
#pragma unroll
      for (int g = 0; g < 4; ++g) {
        const int d0 = dt * 32 + 8 * g + 4 * lh;
        int w0 = cvtpk(o[dt][4 * g] * inv, o[dt][4 * g + 1] * inv);
        int w1 = cvtpk(o[dt][4 * g + 2] * inv, o[dt][4 * g + 3] * inv);
        i32x2 pk = (i32x2){w0, w1};
        *(i32x2*)((u16*)ao + rowoff + d0) = pk;
      }
    // last in-loop barrier already ensured all waves finished LDS reads;
    // next half's stage(0,0) is safe.
  }
}

extern "C" void kernel_launch(void* const* d_in, const int* in_sizes, int n_in,
                              void* d_out, int out_size, void* d_ws, size_t ws_size,
                              hipStream_t stream) {
  const float* x = (const float*)d_in[0];
  const float* fc = (const float*)d_in[1];
  const float* wq = (const float*)d_in[2];
  const float* wk = (const float*)d_in[3];
  const float* wv = (const float*)d_in[4];
  const float* wo = (const float*)d_in[5];
  const float* qw = (const float*)d_in[6];
  const float* kw = (const float*)d_in[7];
  float* out = (float*)d_out;
  char* ws = (char*)d_ws;

  u16* xb    = (u16*)(ws);                 // [4096][2048] bf16   16 MB
  u16* wqkvb = (u16*)(ws + 16777216);      // [4096][2048] bf16   16 MB
  u16* wob   = (u16*)(ws + 33554432);      // [2048][2048] bf16    8 MB
  u16* qkv   = (u16*)(ws + 41943040);      // [4096][4096] bf16   32 MB
  u16* qrope = (u16*)(ws + 75497472);      // [2][16][2048][128]  16 MB
  u16* krope = (u16*)(ws + 92274688);      // [2][8][2048][128]    8 MB
  u16* vtb   = (u16*)(ws + 100663296);     // [2][8][128][2048]    8 MB
  u16* ao    = (u16*)(ws + 109051904);     // [4096][2048] bf16   16 MB

  cvt_all<<<20480, 256, 0, stream>>>(x, wq, wk, wv, wo, xb, wqkvb, wob);

  gemm_bt2<0><<<1024, 256, 0, stream>>>(xb, wqkvb, (void*)qkv, 4096, 4096, 2048, 32);

  rmsnorm_rope<<<24576, 256, 0, stream>>>(qkv, fc, qw, kw, qrope, krope);
  v_transpose<<<512, 256, 0, stream>>>(qkv, vtb);

  attn5<<<256, 256, 0, stream>>>(qrope, krope, vtb, ao);

  gemm_bt2<1><<<512, 256, 0, stream>>>(ao, wob, (void*)out, 4096, 2048, 2048, 16);
}

// Round 7
// 217.048 us; speedup vs baseline: 3.0929x; 1.0360x over previous
//
#include <hip/hip_runtime.h>

#define B_ 2
#define S_ 2048
#define D_ 2048
#define NH 16
#define NKV 8
#define HD 128
#define SCALE 0.08838834764831845f
#define CEXP 0.1275255f          // SCALE * log2(e)
#define RTHR 62.733f             // 8 / CEXP  (defer-max threshold, p <= 2^8)

typedef unsigned short u16;
typedef __attribute__((ext_vector_type(8))) short short8;
typedef __attribute__((ext_vector_type(4))) float f32x4;
typedef __attribute__((ext_vector_type(16))) float f32x16;
typedef __attribute__((ext_vector_type(4))) int i32x4;
typedef __attribute__((ext_vector_type(2))) int i32x2;

#define ASM_VMCNT(N) asm volatile("s_waitcnt vmcnt(" #N ")" ::: "memory")
#define SBAR do { __builtin_amdgcn_sched_barrier(0); __builtin_amdgcn_s_barrier(); __builtin_amdgcn_sched_barrier(0); } while (0)
#define LGKM0 do { asm volatile("s_waitcnt lgkmcnt(0)" ::: "memory"); __builtin_amdgcn_sched_barrier(0); } while (0)

__device__ __forceinline__ u16 f2b(float f) {
  union { float f; unsigned u; } c; c.f = f;
  unsigned u = c.u;
  return (u16)((u + 0x7fffu + ((u >> 16) & 1u)) >> 16);
}
__device__ __forceinline__ float b2f(u16 h) {
  union { unsigned u; float f; } c; c.u = ((unsigned)h) << 16;
  return c.f;
}
__device__ __forceinline__ float exp2f_fast(float x) {
  float r; asm("v_exp_f32 %0, %1" : "=v"(r) : "v"(x)); return r;
}
__device__ __forceinline__ int cvtpk(float a, float b) {  // low16=bf16(a), high16=bf16(b)
  int r; asm("v_cvt_pk_bf16_f32 %0, %1, %2" : "=v"(r) : "v"(a), "v"(b)); return r;
}
// swap: a.hi32lanes <-> b.lo32lanes (both regs updated)
__device__ __forceinline__ void pl32swap(int& a, int& b) {
  asm volatile("v_permlane32_swap_b32 %0, %1" : "+v"(a), "+v"(b));
}

__device__ __forceinline__ void load_lds16(const u16* g, u16* l) {
  __builtin_amdgcn_global_load_lds(
      (const __attribute__((address_space(1))) unsigned int*)g,
      (__attribute__((address_space(3))) unsigned int*)l, 16, 0, 0);
}

// ---------------- fused f32 -> bf16 conversion (all 5 tensors, 1 launch) ----------------
__global__ __launch_bounds__(256) void cvt_all(const float* __restrict__ x,
                                               const float* __restrict__ wq,
                                               const float* __restrict__ wk,
                                               const float* __restrict__ wv,
                                               const float* __restrict__ wo,
                                               u16* __restrict__ xb,
                                               u16* __restrict__ wqkvb,
                                               u16* __restrict__ wob) {
  const int blk = blockIdx.x;
  const float* src; u16* dst; int base;
  if (blk < 8192)       { src = x;  dst = xb;                  base = blk; }
  else if (blk < 12288) { src = wq; dst = wqkvb;               base = blk - 8192; }
  else if (blk < 14336) { src = wk; dst = wqkvb + 2048 * 2048; base = blk - 12288; }
  else if (blk < 16384) { src = wv; dst = wqkvb + 3072 * 2048; base = blk - 14336; }
  else                  { src = wo; dst = wob;                 base = blk - 16384; }
  int i = base * 256 + threadIdx.x;
  float4 v = ((const float4*)src)[i];
  u16 o0 = f2b(v.x), o1 = f2b(v.y), o2 = f2b(v.z), o3 = f2b(v.w);
  unsigned long long packed = (unsigned long long)o0 | ((unsigned long long)o1 << 16) |
                              ((unsigned long long)o2 << 32) | ((unsigned long long)o3 << 48);
  ((unsigned long long*)dst)[i] = packed;
}

// ---------------- GEMM 256x256 8-wave, 4-phase/K-tile, counted vmcnt ----------------
// C[M,N] = A[M,K]*B[N,K]^T. LDS halves [dbuf][kc][256x32] (k-split keeps gload_lds linear).
// swizzle: LDS slot s of row holds k-group s ^ ((row>>1)&3); inverse applied on global src.
#define LDA4(dst, SRC, MI0) \
  { _Pragma("unroll") for (int i2 = 0; i2 < 4; ++i2) { \
      const int arow = wr * 128 + (MI0 + i2) * 16 + r; \
      dst[i2] = *(const short8*)&(SRC)[arow * 32 + ((hi ^ ((arow >> 1) & 3)) << 3)]; } }
#define LDB4(dst, SRC) \
  { _Pragma("unroll") for (int n2 = 0; n2 < 4; ++n2) { \
      const int brow = wc * 64 + n2 * 16 + r; \
      dst[n2] = *(const short8*)&(SRC)[brow * 32 + ((hi ^ ((brow >> 1) & 3)) << 3)]; } }
#define MFMA16(MI0, AF, BF) \
  { __builtin_amdgcn_s_setprio(1); \
    _Pragma("unroll") for (int i2 = 0; i2 < 4; ++i2) \
    _Pragma("unroll") for (int n2 = 0; n2 < 4; ++n2) \
      acc[MI0 + i2][n2] = __builtin_amdgcn_mfma_f32_16x16x32_bf16(AF[i2], BF[n2], acc[MI0 + i2][n2], 0, 0, 0); \
    __builtin_amdgcn_s_setprio(0); }

template<int OUTF32>
__global__ __launch_bounds__(512, 2) void gemm256(const u16* __restrict__ A, const u16* __restrict__ Bm,
                                                  void* __restrict__ Cv, int M, int N, int K, int nbn) {
  __shared__ __align__(16) u16 As[2][2][8192];   // 64 KB
  __shared__ __align__(16) u16 Bs[2][2][8192];   // 64 KB
  const int tid = threadIdx.x;
  const int wave = tid >> 6, lane = tid & 63;
  const int cpx = gridDim.x >> 3;
  const int L = (blockIdx.x & 7) * cpx + (blockIdx.x >> 3);
  const int bm = L / nbn, bn = L % nbn;
  const int wr = wave >> 2, wc = wave & 3;       // 2M x 4N wave grid; per-wave 128x64
  const int r = lane & 15, hi = lane >> 4;
  const int rowA0 = bm * 256, rowB0 = bn * 256;

  f32x4 acc[8][4];
#pragma unroll
  for (int mi = 0; mi < 8; ++mi)
#pragma unroll
    for (int ni = 0; ni < 4; ++ni) acc[mi][ni] = (f32x4){0.f, 0.f, 0.f, 0.f};

  // stage one 16KB half (256 rows x 32 k): 2 x gload_lds per thread, linear LDS dest,
  // inverse-swizzled global source.
  auto stage_half = [&](const u16* G, int rowbase, u16* ldsb, int kcol) {
#pragma unroll
    for (int l = 0; l < 2; ++l) {
      const int p = wave * 2048 + l * 1024 + lane * 16;  // byte pos in half
      const int row = p >> 6, slot = (p >> 4) & 3;
      const int kg = slot ^ ((row >> 1) & 3);
      load_lds16(G + (size_t)(rowbase + row) * K + kcol + kg * 8,
                 ldsb + ((wave * 2048 + l * 1024) >> 1));
    }
  };

  // prologue: halves 0..3 of K-tile 0; certify halves 0,1 (A-k0,B-k0)
  stage_half(A,  rowA0, &As[0][0][0], 0);
  stage_half(Bm, rowB0, &Bs[0][0][0], 0);
  stage_half(A,  rowA0, &As[0][1][0], 32);
  stage_half(Bm, rowB0, &Bs[0][1][0], 32);
  ASM_VMCNT(4);
  __builtin_amdgcn_s_barrier();

  const int nk = K >> 6;
  for (int kt = 0; kt < nk; ++kt) {
    const int c = kt & 1, nb2 = c ^ 1;
    const int kn = (kt + 1) << 6;
    const bool hn = kt + 1 < nk;
    const u16* a0 = As[c][0]; const u16* b0 = Bs[c][0];
    const u16* a1 = As[c][1]; const u16* b1 = Bs[c][1];
    short8 af[4], bf[4];
    // ---- phase 0 (kc=0, mi 0-3): 8 ds_read, stage A-k0 of kt+1
    LDB4(bf, b0); LDA4(af, a0, 0);
    if (hn) stage_half(A, rowA0, &As[nb2][0][0], kn);
    SBAR; LGKM0;
    MFMA16(0, af, bf);
    SBAR;
    // ---- phase 1 (kc=0, mi 4-7): 4 ds_read, stage B-k0, vmcnt(4) certifies halves kt.2/3
    LDA4(af, a0, 4);
    if (hn) stage_half(Bm, rowB0, &Bs[nb2][0][0], kn);
    ASM_VMCNT(4);
    SBAR; LGKM0;
    MFMA16(4, af, bf);
    SBAR;
    // ---- phase 2 (kc=1, mi 0-3): 8 ds_read, stage A-k1
    LDB4(bf, b1); LDA4(af, a1, 0);
    if (hn) stage_half(A, rowA0, &As[nb2][1][0], kn + 32);
    SBAR; LGKM0;
    MFMA16(0, af, bf);
    SBAR;
    // ---- phase 3 (kc=1, mi 4-7): 4 ds_read, stage B-k1, vmcnt(4) certifies next tile .0/.1
    LDA4(af, a1, 4);
    if (hn) stage_half(Bm, rowB0, &Bs[nb2][1][0], kn + 32);
    ASM_VMCNT(4);
    SBAR; LGKM0;
    MFMA16(4, af, bf);
    SBAR;
  }

#pragma unroll
  for (int mi = 0; mi < 8; ++mi)
#pragma unroll
    for (int ni = 0; ni < 4; ++ni)
#pragma unroll
      for (int r2 = 0; r2 < 4; ++r2) {
        int grow = bm * 256 + wr * 128 + mi * 16 + hi * 4 + r2;
        int gcol = bn * 256 + wc * 64 + ni * 16 + r;
        if (OUTF32)
          ((float*)Cv)[(size_t)grow * N + gcol] = acc[mi][ni][r2];
        else
          ((u16*)Cv)[(size_t)grow * N + gcol] = f2b(acc[mi][ni][r2]);
      }
}

// ---------------- GEMM v2 (128^2): kept for the N=2048 output GEMM ----------------
template<int OUTF32>
__global__ __launch_bounds__(256, 2) void gemm_bt2(const u16* __restrict__ A, const u16* __restrict__ Bm,
                                                   void* __restrict__ Cv, int M, int N, int K, int nbn) {
  __shared__ __align__(16) u16 As[2][128 * 64];
  __shared__ __align__(16) u16 Bs[2][128 * 64];
  const int tid = threadIdx.x;
  const int wave = tid >> 6, lane = tid & 63;
  const int nwg = gridDim.x, cpx = nwg >> 3;
  const int L = (blockIdx.x & 7) * cpx + (blockIdx.x >> 3);
  const int bm = L / nbn, bn = L % nbn;
  const int wr = wave >> 1, wc = wave & 1;
  const int r = lane & 15, hi = lane >> 4;

  f32x4 acc[4][4];
#pragma unroll
  for (int m = 0; m < 4; ++m)
#pragma unroll
    for (int n = 0; n < 4; ++n) acc[m][n] = (f32x4){0.f, 0.f, 0.f, 0.f};

  const int gslot = (lane & 7) ^ (lane >> 3);
  const int srow = lane >> 3;

  auto stage = [&](int buf, int k0) {
#pragma unroll
    for (int jj = 0; jj < 4; ++jj) {
      int j = wave * 4 + jj;
      int row = j * 8 + srow;
      load_lds16(A + (size_t)(bm * 128 + row) * K + k0 + gslot * 8, &As[buf][j * 512]);
      load_lds16(Bm + (size_t)(bn * 128 + row) * K + k0 + gslot * 8, &Bs[buf][j * 512]);
    }
  };

  const int nk = K >> 6;
  stage(0, 0);
  for (int kt = 0; kt < nk; ++kt) {
    if (kt + 1 < nk) {
      stage((kt + 1) & 1, (kt + 1) << 6);
      ASM_VMCNT(8);
    } else {
      ASM_VMCNT(0);
    }
    SBAR;
    const u16* as = As[kt & 1];
    const u16* bs = Bs[kt & 1];
#pragma unroll
    for (int kc = 0; kc < 2; ++kc) {
      short8 af[4], bfr[4];
#pragma unroll
      for (int m = 0; m < 4; ++m) {
        int row = wr * 64 + m * 16 + r;
        int slot = (hi + kc * 4) ^ (row & 7);
        af[m] = *(const short8*)&as[row * 64 + slot * 8];
      }
#pragma unroll
      for (int n = 0; n < 4; ++n) {
        int row = wc * 64 + n * 16 + r;
        int slot = (hi + kc * 4) ^ (row & 7);
        bfr[n] = *(const short8*)&bs[row * 64 + slot * 8];
      }
#pragma unroll
      for (int m = 0; m < 4; ++m)
#pragma unroll
        for (int n = 0; n < 4; ++n)
          acc[m][n] = __builtin_amdgcn_mfma_f32_16x16x32_bf16(af[m], bfr[n], acc[m][n], 0, 0, 0);
    }
    SBAR;
  }

#pragma unroll
  for (int m = 0; m < 4; ++m)
#pragma unroll
    for (int n = 0; n < 4; ++n)
#pragma unroll
      for (int r2 = 0; r2 < 4; ++r2) {
        int grow = bm * 128 + wr * 64 + m * 16 + hi * 4 + r2;
        int gcol = bn * 128 + wc * 64 + n * 16 + r;
        if (OUTF32)
          ((float*)Cv)[(size_t)grow * N + gcol] = acc[m][n][r2];
        else
          ((u16*)Cv)[(size_t)grow * N + gcol] = f2b(acc[m][n][r2]);
      }
}

// ---------------- per-head RMSNorm + RoPE for Q and K ----------------
__global__ __launch_bounds__(256) void rmsnorm_rope(const u16* __restrict__ qkv, const float* __restrict__ fc,
                                                    const float* __restrict__ qw, const float* __restrict__ kw,
                                                    u16* __restrict__ qr, u16* __restrict__ kr) {
  const int tid = threadIdx.x, wave = tid >> 6, lane = tid & 63;
  const int rowid = blockIdx.x * 4 + wave;
  const int token = rowid / 24;
  const int hh = rowid % 24;
  const int b = token >> 11, s = token & 2047;
  const bool isq = hh < 16;
  const int off = isq ? hh * 128 : 2048 + (hh - 16) * 128;
  const u16* src = qkv + (size_t)token * 4096 + off + lane * 2;
  unsigned pv = *(const unsigned*)src;
  float t0 = b2f((u16)(pv & 0xffffu));
  float t1 = b2f((u16)(pv >> 16));
  float ss = t0 * t0 + t1 * t1;
#pragma unroll
  for (int mm = 1; mm < 64; mm <<= 1) ss += __shfl_xor(ss, mm, 64);
  float rms = rsqrtf(ss * (1.0f / 128.0f) + 1e-6f);
  const float* nw = isq ? qw : kw;
  t0 *= rms * nw[lane * 2];
  t1 *= rms * nw[lane * 2 + 1];
  float c = fc[(s * 64 + lane) * 2], sn = fc[(s * 64 + lane) * 2 + 1];
  float o0 = t0 * c - t1 * sn;
  float o1 = t0 * sn + t1 * c;
  unsigned ov = (unsigned)f2b(o0) | ((unsigned)f2b(o1) << 16);
  if (isq)
    *(unsigned*)(qr + ((size_t)(b * 16 + hh) * 2048 + s) * 128 + lane * 2) = ov;
  else
    *(unsigned*)(kr + ((size_t)(b * 8 + hh - 16) * 2048 + s) * 128 + lane * 2) = ov;
}

// ---------------- V transpose: qkv v-section -> vt[b][hkv][d][s] ----------------
__global__ __launch_bounds__(256) void v_transpose(const u16* __restrict__ qkv, u16* __restrict__ vt) {
  __shared__ __align__(16) u16 tile[64][136];
  const int blk = blockIdx.x;
  const int st = blk & 31, h = (blk >> 5) & 7, b = blk >> 8;
  const int s0 = st * 64, t = threadIdx.x;
#pragma unroll
  for (int p = 0; p < 4; ++p) {
    int row = p * 16 + (t >> 4), c8 = (t & 15) * 8;
    const u16* src = qkv + (size_t)(b * 2048 + s0 + row) * 4096 + 3072 + h * 128 + c8;
    *(short8*)&tile[row][c8] = *(const short8*)src;
  }
  __syncthreads();
  const int d = t >> 1, j0 = (t & 1) * 32;
  u16* dst = vt + ((size_t)(b * 8 + h) * 128 + d) * 2048 + s0 + j0;
#pragma unroll
  for (int j = 0; j < 32; j += 8) {
    short8 v;
#pragma unroll
    for (int u = 0; u < 8; ++u) v[u] = (short)tile[j0 + j + u][d];
    *(short8*)(dst + j) = v;
  }
}

// ---------------- causal flash attention v5: static paired tiles ----------------
__global__ __launch_bounds__(256, 2) void attn5(const u16* __restrict__ qr, const u16* __restrict__ kr,
                                                const u16* __restrict__ vt, u16* __restrict__ ao) {
  __shared__ __align__(16) u16 Ks[2][64 * 128];
  __shared__ __align__(16) u16 Vs[2][128 * 64];
  const int tid = threadIdx.x, wave = tid >> 6, lane = tid & 63;
  const int ql = lane & 31, lh = lane >> 5;

  const int xcd = blockIdx.x & 7, idx = blockIdx.x >> 3;
  const int bh = xcd * 4 + (idx & 3);
  const int p = idx >> 2;
  const int b = bh >> 4, h = bh & 15, hkv = h >> 1;

  const u16* Q  = qr + (size_t)(b * 16 + h) * S_ * HD;
  const u16* Kg = kr + (size_t)(b * 8 + hkv) * S_ * HD;
  const u16* Vg = vt + (size_t)(b * 8 + hkv) * HD * S_;

  auto stage = [&](int buf, int kv0) {
#pragma unroll
    for (int inst = 0; inst < 4; ++inst) {
      int pp = wave * 4096 + inst * 1024 + lane * 16;
      int row = pp >> 8;
      int colb = (pp & 255) ^ ((row & 7) << 4);
      load_lds16(Kg + (((size_t)(kv0 + row)) << 7) + (colb >> 1),
                 &Ks[buf][(wave * 4096 + inst * 1024) >> 1]);
    }
#pragma unroll
    for (int inst = 0; inst < 4; ++inst) {
      int pp = wave * 4096 + inst * 1024 + lane * 16;
      int d = pp >> 7;
      int colb = (pp & 127) ^ ((d & 7) << 4);
      load_lds16(Vg + (size_t)d * S_ + kv0 + (colb >> 1),
                 &Vs[buf][(wave * 4096 + inst * 1024) >> 1]);
    }
  };

#pragma unroll 1
  for (int half = 0; half < 2; ++half) {
    const int t = half ? p : 15 - p;
    const int q0w = t * 128 + wave * 32;
    const int nsteps = 2 * (t + 1);

    short8 qf[8];
#pragma unroll
    for (int ki = 0; ki < 8; ++ki)
      qf[ki] = *(const short8*)(Q + (size_t)(q0w + ql) * HD + ki * 16 + lh * 8);

    f32x16 o[4];
#pragma unroll
    for (int dt = 0; dt < 4; ++dt) o[dt] = 0.f;
    float m = -1e30f, l = 0.f;

    stage(0, 0);
    for (int i = 0; i < nsteps; ++i) {
      const int kv0 = i * 64;
      const u16* kb = Ks[i & 1];
      const u16* vb = Vs[i & 1];
      if (i + 1 < nsteps) {
        stage((i + 1) & 1, kv0 + 64);
        ASM_VMCNT(8);
      } else {
        ASM_VMCNT(0);
      }
      SBAR;

      if (kv0 < q0w + 32) {
        f32x16 sacc[2];
        sacc[0] = 0.f; sacc[1] = 0.f;
        __builtin_amdgcn_s_setprio(1);
#pragma unroll
        for (int ki = 0; ki < 8; ++ki) {
          const int off = ki * 32 + lh * 16;
#pragma unroll
          for (int kvt = 0; kvt < 2; ++kvt) {
            const int row = kvt * 32 + ql;
            short8 kf = *(const short8*)&kb[(row << 7) + ((off ^ ((row & 7) << 4)) >> 1)];
            sacc[kvt] = __builtin_amdgcn_mfma_f32_32x32x16_bf16(kf, qf[ki], sacc[kvt], 0, 0, 0);
          }
        }
        __builtin_amdgcn_s_setprio(0);
        const int q = q0w + ql;
        if (kv0 + 64 > q0w) {
#pragma unroll
          for (int kvt = 0; kvt < 2; ++kvt) {
            const int kvb = kv0 + kvt * 32 + 4 * lh;
#pragma unroll
            for (int reg = 0; reg < 16; ++reg) {
              const int kvr = kvb + (reg & 3) + 8 * (reg >> 2);
              sacc[kvt][reg] = (kvr > q) ? -1e30f : sacc[kvt][reg];
            }
          }
        }
        float mx = sacc[0][0];
#pragma unroll
        for (int kvt = 0; kvt < 2; ++kvt)
#pragma unroll
          for (int reg = 0; reg < 16; ++reg) mx = fmaxf(mx, sacc[kvt][reg]);
        mx = fmaxf(mx, __shfl_xor(mx, 32, 64));
        if (__any(mx > m + RTHR)) {
          float mn = fmaxf(m, mx);
          float sc = exp2f_fast((m - mn) * CEXP);
          l *= sc;
          m = mn;
#pragma unroll
          for (int dt = 0; dt < 4; ++dt)
#pragma unroll
            for (int reg = 0; reg < 16; ++reg) o[dt][reg] *= sc;
        }
        short8 pf[4];
        const float mc = m * CEXP;
        float ps = 0.f;
#pragma unroll
        for (int kvt = 0; kvt < 2; ++kvt) {
          float pv[16];
#pragma unroll
          for (int reg = 0; reg < 16; ++reg) {
            pv[reg] = exp2f_fast(__builtin_fmaf(sacc[kvt][reg], CEXP, -mc));
            ps += pv[reg];
          }
          int A0 = cvtpk(pv[0], pv[1]),  B0 = cvtpk(pv[2], pv[3]);
          int C0 = cvtpk(pv[4], pv[5]),  D0 = cvtpk(pv[6], pv[7]);
          int A1 = cvtpk(pv[8], pv[9]),  B1 = cvtpk(pv[10], pv[11]);
          int C1 = cvtpk(pv[12], pv[13]), D1 = cvtpk(pv[14], pv[15]);
          pl32swap(A0, C0);
          pl32swap(B0, D0);
          pl32swap(A1, C1);
          pl32swap(B1, D1);
          i32x4 w0 = (i32x4){A0, B0, C0, D0};
          i32x4 w1 = (i32x4){A1, B1, C1, D1};
          pf[kvt * 2]     = *(short8*)&w0;
          pf[kvt * 2 + 1] = *(short8*)&w1;
        }
        l += ps;
        __builtin_amdgcn_s_setprio(1);
#pragma unroll
        for (int kc = 0; kc < 4; ++kc) {
          const int off = kc * 32 + lh * 16;
#pragma unroll
          for (int dt = 0; dt < 4; ++dt) {
            const int d = dt * 32 + ql;
            short8 vf = *(const short8*)&vb[(d << 6) + ((off ^ ((d & 7) << 4)) >> 1)];
            o[dt] = __builtin_amdgcn_mfma_f32_32x32x16_bf16(vf, pf[kc], o[dt], 0, 0, 0);
          }
        }
        __builtin_amdgcn_s_setprio(0);
      }
      SBAR;
    }

    l += __shfl_xor(l, 32, 64);
    const float inv = 1.0f / l;
    const size_t rowoff = ((size_t)(b * 2048 + q0w + ql)) * 2048 + h * 128;
#pragma unroll
    for (int dt = 0; dt < 4; ++dt)
#pragma unroll
      for (int g = 0; g < 4; ++g) {
        const int d0 = dt * 32 + 8 * g + 4 * lh;
        int w0 = cvtpk(o[dt][4 * g] * inv, o[dt][4 * g + 1] * inv);
        int w1 = cvtpk(o[dt][4 * g + 2] * inv, o[dt][4 * g + 3] * inv);
        i32x2 pk = (i32x2){w0, w1};
        *(i32x2*)((u16*)ao + rowoff + d0) = pk;
      }
  }
}

extern "C" void kernel_launch(void* const* d_in, const int* in_sizes, int n_in,
                              void* d_out, int out_size, void* d_ws, size_t ws_size,
                              hipStream_t stream) {
  const float* x = (const float*)d_in[0];
  const float* fc = (const float*)d_in[1];
  const float* wq = (const float*)d_in[2];
  const float* wk = (const float*)d_in[3];
  const float* wv = (const float*)d_in[4];
  const float* wo = (const float*)d_in[5];
  const float* qw = (const float*)d_in[6];
  const float* kw = (const float*)d_in[7];
  float* out = (float*)d_out;
  char* ws = (char*)d_ws;

  u16* xb    = (u16*)(ws);                 // [4096][2048] bf16   16 MB
  u16* wqkvb = (u16*)(ws + 16777216);      // [4096][2048] bf16   16 MB
  u16* wob   = (u16*)(ws + 33554432);      // [2048][2048] bf16    8 MB
  u16* qkv   = (u16*)(ws + 41943040);      // [4096][4096] bf16   32 MB
  u16* qrope = (u16*)(ws + 75497472);      // [2][16][2048][128]  16 MB
  u16* krope = (u16*)(ws + 92274688);      // [2][8][2048][128]    8 MB
  u16* vtb   = (u16*)(ws + 100663296);     // [2][8][128][2048]    8 MB
  u16* ao    = (u16*)(ws + 109051904);     // [4096][2048] bf16   16 MB

  cvt_all<<<20480, 256, 0, stream>>>(x, wq, wk, wv, wo, xb, wqkvb, wob);

  gemm256<0><<<256, 512, 0, stream>>>(xb, wqkvb, (void*)qkv, 4096, 4096, 2048, 16);

  rmsnorm_rope<<<24576, 256, 0, stream>>>(qkv, fc, qw, kw, qrope, krope);
  v_transpose<<<512, 256, 0, stream>>>(qkv, vtb);

  attn5<<<256, 256, 0, stream>>>(qrope, krope, vtb, ao);

  gemm_bt2<1><<<512, 256, 0, stream>>>(ao, wob, (void*)out, 4096, 2048, 2048, 16);
}

// Round 8
// 212.815 us; speedup vs baseline: 3.1544x; 1.0199x over previous
//
#include <hip/hip_runtime.h>

#define B_ 2
#define S_ 2048
#define D_ 2048
#define NH 16
#define NKV 8
#define HD 128
#define SCALE 0.08838834764831845f
#define CEXP 0.1275255f          // SCALE * log2(e)
#define RTHR 62.733f             // 8 / CEXP  (defer-max threshold, p <= 2^8)

typedef unsigned short u16;
typedef __attribute__((ext_vector_type(8))) short short8;
typedef __attribute__((ext_vector_type(4))) float f32x4;
typedef __attribute__((ext_vector_type(16))) float f32x16;
typedef __attribute__((ext_vector_type(4))) int i32x4;
typedef __attribute__((ext_vector_type(2))) int i32x2;

#define ASM_VMCNT(N) asm volatile("s_waitcnt vmcnt(" #N ")" ::: "memory")
#define SBAR do { __builtin_amdgcn_sched_barrier(0); __builtin_amdgcn_s_barrier(); __builtin_amdgcn_sched_barrier(0); } while (0)
#define LGKM0 do { asm volatile("s_waitcnt lgkmcnt(0)" ::: "memory"); __builtin_amdgcn_sched_barrier(0); } while (0)

__device__ __forceinline__ u16 f2b(float f) {
  union { float f; unsigned u; } c; c.f = f;
  unsigned u = c.u;
  return (u16)((u + 0x7fffu + ((u >> 16) & 1u)) >> 16);
}
__device__ __forceinline__ float b2f(u16 h) {
  union { unsigned u; float f; } c; c.u = ((unsigned)h) << 16;
  return c.f;
}
__device__ __forceinline__ float exp2f_fast(float x) {
  float r; asm("v_exp_f32 %0, %1" : "=v"(r) : "v"(x)); return r;
}
__device__ __forceinline__ int cvtpk(float a, float b) {  // low16=bf16(a), high16=bf16(b)
  int r; asm("v_cvt_pk_bf16_f32 %0, %1, %2" : "=v"(r) : "v"(a), "v"(b)); return r;
}
// swap: a.hi32lanes <-> b.lo32lanes (both regs updated)
__device__ __forceinline__ void pl32swap(int& a, int& b) {
  asm volatile("v_permlane32_swap_b32 %0, %1" : "+v"(a), "+v"(b));
}

__device__ __forceinline__ void load_lds16(const u16* g, u16* l) {
  __builtin_amdgcn_global_load_lds(
      (const __attribute__((address_space(1))) unsigned int*)g,
      (__attribute__((address_space(3))) unsigned int*)l, 16, 0, 0);
}

// ---------------- fused f32 -> bf16 conversion (all 5 tensors, 1 launch) ----------------
__global__ __launch_bounds__(256) void cvt_all(const float* __restrict__ x,
                                               const float* __restrict__ wq,
                                               const float* __restrict__ wk,
                                               const float* __restrict__ wv,
                                               const float* __restrict__ wo,
                                               u16* __restrict__ xb,
                                               u16* __restrict__ wqkvb,
                                               u16* __restrict__ wob) {
  const int blk = blockIdx.x;
  const float* src; u16* dst; int base;
  if (blk < 8192)       { src = x;  dst = xb;                  base = blk; }
  else if (blk < 12288) { src = wq; dst = wqkvb;               base = blk - 8192; }
  else if (blk < 14336) { src = wk; dst = wqkvb + 2048 * 2048; base = blk - 12288; }
  else if (blk < 16384) { src = wv; dst = wqkvb + 3072 * 2048; base = blk - 14336; }
  else                  { src = wo; dst = wob;                 base = blk - 16384; }
  int i = base * 256 + threadIdx.x;
  float4 v = ((const float4*)src)[i];
  u16 o0 = f2b(v.x), o1 = f2b(v.y), o2 = f2b(v.z), o3 = f2b(v.w);
  unsigned long long packed = (unsigned long long)o0 | ((unsigned long long)o1 << 16) |
                              ((unsigned long long)o2 << 32) | ((unsigned long long)o3 << 48);
  ((unsigned long long*)dst)[i] = packed;
}

// ---------------- GEMM 256x256 8-wave, 4-phase/K-tile, counted vmcnt ----------------
#define LDA4(dst, SRC, MI0) \
  { _Pragma("unroll") for (int i2 = 0; i2 < 4; ++i2) { \
      const int arow = wr * 128 + (MI0 + i2) * 16 + r; \
      dst[i2] = *(const short8*)&(SRC)[arow * 32 + ((hi ^ ((arow >> 1) & 3)) << 3)]; } }
#define LDB4(dst, SRC) \
  { _Pragma("unroll") for (int n2 = 0; n2 < 4; ++n2) { \
      const int brow = wc * 64 + n2 * 16 + r; \
      dst[n2] = *(const short8*)&(SRC)[brow * 32 + ((hi ^ ((brow >> 1) & 3)) << 3)]; } }
#define MFMA16(MI0, AF, BF) \
  { __builtin_amdgcn_s_setprio(1); \
    _Pragma("unroll") for (int i2 = 0; i2 < 4; ++i2) \
    _Pragma("unroll") for (int n2 = 0; n2 < 4; ++n2) \
      acc[MI0 + i2][n2] = __builtin_amdgcn_mfma_f32_16x16x32_bf16(AF[i2], BF[n2], acc[MI0 + i2][n2], 0, 0, 0); \
    __builtin_amdgcn_s_setprio(0); }

template<int OUTF32>
__global__ __launch_bounds__(512, 2) void gemm256(const u16* __restrict__ A, const u16* __restrict__ Bm,
                                                  void* __restrict__ Cv, int M, int N, int K, int nbn) {
  __shared__ __align__(16) u16 As[2][2][8192];   // 64 KB
  __shared__ __align__(16) u16 Bs[2][2][8192];   // 64 KB
  const int tid = threadIdx.x;
  const int wave = tid >> 6, lane = tid & 63;
  const int cpx = gridDim.x >> 3;
  const int L = (blockIdx.x & 7) * cpx + (blockIdx.x >> 3);
  const int bm = L / nbn, bn = L % nbn;
  const int wr = wave >> 2, wc = wave & 3;       // 2M x 4N wave grid; per-wave 128x64
  const int r = lane & 15, hi = lane >> 4;
  const int rowA0 = bm * 256, rowB0 = bn * 256;

  f32x4 acc[8][4];
#pragma unroll
  for (int mi = 0; mi < 8; ++mi)
#pragma unroll
    for (int ni = 0; ni < 4; ++ni) acc[mi][ni] = (f32x4){0.f, 0.f, 0.f, 0.f};

  auto stage_half = [&](const u16* G, int rowbase, u16* ldsb, int kcol) {
#pragma unroll
    for (int l = 0; l < 2; ++l) {
      const int p = wave * 2048 + l * 1024 + lane * 16;  // byte pos in half
      const int row = p >> 6, slot = (p >> 4) & 3;
      const int kg = slot ^ ((row >> 1) & 3);
      load_lds16(G + (size_t)(rowbase + row) * K + kcol + kg * 8,
                 ldsb + ((wave * 2048 + l * 1024) >> 1));
    }
  };

  stage_half(A,  rowA0, &As[0][0][0], 0);
  stage_half(Bm, rowB0, &Bs[0][0][0], 0);
  stage_half(A,  rowA0, &As[0][1][0], 32);
  stage_half(Bm, rowB0, &Bs[0][1][0], 32);
  ASM_VMCNT(4);
  __builtin_amdgcn_s_barrier();

  const int nk = K >> 6;
  for (int kt = 0; kt < nk; ++kt) {
    const int c = kt & 1, nb2 = c ^ 1;
    const int kn = (kt + 1) << 6;
    const bool hn = kt + 1 < nk;
    const u16* a0 = As[c][0]; const u16* b0 = Bs[c][0];
    const u16* a1 = As[c][1]; const u16* b1 = Bs[c][1];
    short8 af[4], bf[4];
    // ---- phase 0 (kc=0, mi 0-3)
    LDB4(bf, b0); LDA4(af, a0, 0);
    if (hn) stage_half(A, rowA0, &As[nb2][0][0], kn);
    SBAR; LGKM0;
    MFMA16(0, af, bf);
    SBAR;
    // ---- phase 1 (kc=0, mi 4-7)
    LDA4(af, a0, 4);
    if (hn) stage_half(Bm, rowB0, &Bs[nb2][0][0], kn);
    ASM_VMCNT(4);
    SBAR; LGKM0;
    MFMA16(4, af, bf);
    SBAR;
    // ---- phase 2 (kc=1, mi 0-3)
    LDB4(bf, b1); LDA4(af, a1, 0);
    if (hn) stage_half(A, rowA0, &As[nb2][1][0], kn + 32);
    SBAR; LGKM0;
    MFMA16(0, af, bf);
    SBAR;
    // ---- phase 3 (kc=1, mi 4-7)
    LDA4(af, a1, 4);
    if (hn) stage_half(Bm, rowB0, &Bs[nb2][1][0], kn + 32);
    ASM_VMCNT(4);
    SBAR; LGKM0;
    MFMA16(4, af, bf);
    SBAR;
  }

#pragma unroll
  for (int mi = 0; mi < 8; ++mi)
#pragma unroll
    for (int ni = 0; ni < 4; ++ni)
#pragma unroll
      for (int r2 = 0; r2 < 4; ++r2) {
        int grow = bm * 256 + wr * 128 + mi * 16 + hi * 4 + r2;
        int gcol = bn * 256 + wc * 64 + ni * 16 + r;
        if (OUTF32)
          ((float*)Cv)[(size_t)grow * N + gcol] = acc[mi][ni][r2];
        else
          ((u16*)Cv)[(size_t)grow * N + gcol] = f2b(acc[mi][ni][r2]);
      }
}

// ---------------- GEMM v2 (128^2): kept for the N=2048 output GEMM ----------------
template<int OUTF32>
__global__ __launch_bounds__(256, 2) void gemm_bt2(const u16* __restrict__ A, const u16* __restrict__ Bm,
                                                   void* __restrict__ Cv, int M, int N, int K, int nbn) {
  __shared__ __align__(16) u16 As[2][128 * 64];
  __shared__ __align__(16) u16 Bs[2][128 * 64];
  const int tid = threadIdx.x;
  const int wave = tid >> 6, lane = tid & 63;
  const int nwg = gridDim.x, cpx = nwg >> 3;
  const int L = (blockIdx.x & 7) * cpx + (blockIdx.x >> 3);
  const int bm = L / nbn, bn = L % nbn;
  const int wr = wave >> 1, wc = wave & 1;
  const int r = lane & 15, hi = lane >> 4;

  f32x4 acc[4][4];
#pragma unroll
  for (int m = 0; m < 4; ++m)
#pragma unroll
    for (int n = 0; n < 4; ++n) acc[m][n] = (f32x4){0.f, 0.f, 0.f, 0.f};

  const int gslot = (lane & 7) ^ (lane >> 3);
  const int srow = lane >> 3;

  auto stage = [&](int buf, int k0) {
#pragma unroll
    for (int jj = 0; jj < 4; ++jj) {
      int j = wave * 4 + jj;
      int row = j * 8 + srow;
      load_lds16(A + (size_t)(bm * 128 + row) * K + k0 + gslot * 8, &As[buf][j * 512]);
      load_lds16(Bm + (size_t)(bn * 128 + row) * K + k0 + gslot * 8, &Bs[buf][j * 512]);
    }
  };

  const int nk = K >> 6;
  stage(0, 0);
  for (int kt = 0; kt < nk; ++kt) {
    if (kt + 1 < nk) {
      stage((kt + 1) & 1, (kt + 1) << 6);
      ASM_VMCNT(8);
    } else {
      ASM_VMCNT(0);
    }
    SBAR;
    const u16* as = As[kt & 1];
    const u16* bs = Bs[kt & 1];
#pragma unroll
    for (int kc = 0; kc < 2; ++kc) {
      short8 af[4], bfr[4];
#pragma unroll
      for (int m = 0; m < 4; ++m) {
        int row = wr * 64 + m * 16 + r;
        int slot = (hi + kc * 4) ^ (row & 7);
        af[m] = *(const short8*)&as[row * 64 + slot * 8];
      }
#pragma unroll
      for (int n = 0; n < 4; ++n) {
        int row = wc * 64 + n * 16 + r;
        int slot = (hi + kc * 4) ^ (row & 7);
        bfr[n] = *(const short8*)&bs[row * 64 + slot * 8];
      }
#pragma unroll
      for (int m = 0; m < 4; ++m)
#pragma unroll
        for (int n = 0; n < 4; ++n)
          acc[m][n] = __builtin_amdgcn_mfma_f32_16x16x32_bf16(af[m], bfr[n], acc[m][n], 0, 0, 0);
    }
    SBAR;
  }

#pragma unroll
  for (int m = 0; m < 4; ++m)
#pragma unroll
    for (int n = 0; n < 4; ++n)
#pragma unroll
      for (int r2 = 0; r2 < 4; ++r2) {
        int grow = bm * 128 + wr * 64 + m * 16 + hi * 4 + r2;
        int gcol = bn * 128 + wc * 64 + n * 16 + r;
        if (OUTF32)
          ((float*)Cv)[(size_t)grow * N + gcol] = acc[m][n][r2];
        else
          ((u16*)Cv)[(size_t)grow * N + gcol] = f2b(acc[m][n][r2]);
      }
}

// ---------------- per-head RMSNorm + RoPE for Q and K ----------------
__global__ __launch_bounds__(256) void rmsnorm_rope(const u16* __restrict__ qkv, const float* __restrict__ fc,
                                                    const float* __restrict__ qw, const float* __restrict__ kw,
                                                    u16* __restrict__ qr, u16* __restrict__ kr) {
  const int tid = threadIdx.x, wave = tid >> 6, lane = tid & 63;
  const int rowid = blockIdx.x * 4 + wave;
  const int token = rowid / 24;
  const int hh = rowid % 24;
  const int b = token >> 11, s = token & 2047;
  const bool isq = hh < 16;
  const int off = isq ? hh * 128 : 2048 + (hh - 16) * 128;
  const u16* src = qkv + (size_t)token * 4096 + off + lane * 2;
  unsigned pv = *(const unsigned*)src;
  float t0 = b2f((u16)(pv & 0xffffu));
  float t1 = b2f((u16)(pv >> 16));
  float ss = t0 * t0 + t1 * t1;
#pragma unroll
  for (int mm = 1; mm < 64; mm <<= 1) ss += __shfl_xor(ss, mm, 64);
  float rms = rsqrtf(ss * (1.0f / 128.0f) + 1e-6f);
  const float* nw = isq ? qw : kw;
  t0 *= rms * nw[lane * 2];
  t1 *= rms * nw[lane * 2 + 1];
  float c = fc[(s * 64 + lane) * 2], sn = fc[(s * 64 + lane) * 2 + 1];
  float o0 = t0 * c - t1 * sn;
  float o1 = t0 * sn + t1 * c;
  unsigned ov = (unsigned)f2b(o0) | ((unsigned)f2b(o1) << 16);
  if (isq)
    *(unsigned*)(qr + ((size_t)(b * 16 + hh) * 2048 + s) * 128 + lane * 2) = ov;
  else
    *(unsigned*)(kr + ((size_t)(b * 8 + hh - 16) * 2048 + s) * 128 + lane * 2) = ov;
}

// ---------------- V transpose: qkv v-section -> vt[b][hkv][d][s] ----------------
__global__ __launch_bounds__(256) void v_transpose(const u16* __restrict__ qkv, u16* __restrict__ vt) {
  __shared__ __align__(16) u16 tile[64][136];
  const int blk = blockIdx.x;
  const int st = blk & 31, h = (blk >> 5) & 7, b = blk >> 8;
  const int s0 = st * 64, t = threadIdx.x;
#pragma unroll
  for (int p = 0; p < 4; ++p) {
    int row = p * 16 + (t >> 4), c8 = (t & 15) * 8;
    const u16* src = qkv + (size_t)(b * 2048 + s0 + row) * 4096 + 3072 + h * 128 + c8;
    *(short8*)&tile[row][c8] = *(const short8*)src;
  }
  __syncthreads();
  const int d = t >> 1, j0 = (t & 1) * 32;
  u16* dst = vt + ((size_t)(b * 8 + h) * 128 + d) * 2048 + s0 + j0;
#pragma unroll
  for (int j = 0; j < 32; j += 8) {
    short8 v;
#pragma unroll
    for (int u = 0; u < 8; ++u) v[u] = (short)tile[j0 + j + u][d];
    *(short8*)(dst + j) = v;
  }
}

// ---------------- causal flash attention v6: one tile/block, complementary pairing ----------------
// 512 blocks (2/CU): blocks k and k+256 carry the same (bh, pp) with t = 15-pp and t = pp
// (t1+t2 = 15 -> every CU gets exactly 34 steps, two co-resident blocks, shared-bh L2/L1).
// 4 waves x 32 q-rows; KVBLK=64; dbuf XOR-swizzled LDS; swapped QK^T / PV; permlane repack.
__global__ __launch_bounds__(256, 2) void attn6(const u16* __restrict__ qr, const u16* __restrict__ kr,
                                                const u16* __restrict__ vt, u16* __restrict__ ao) {
  __shared__ __align__(16) u16 Ks[2][64 * 128];
  __shared__ __align__(16) u16 Vs[2][128 * 64];
  const int tid = threadIdx.x, wave = tid >> 6, lane = tid & 63;
  const int ql = lane & 31, lh = lane >> 5;

  const int blk = blockIdx.x;
  const int half = blk >> 8;                 // 0: big tiles, 1: complementary small tiles
  const int xcd = blk & 7;
  const int idx = (blk >> 3) & 31;
  const int bh = xcd * 4 + (idx & 3);
  const int pp = idx >> 2;                   // 0..7
  const int t = half ? pp : 15 - pp;
  const int b = bh >> 4, h = bh & 15, hkv = h >> 1;

  const u16* Q  = qr + (size_t)(b * 16 + h) * S_ * HD;
  const u16* Kg = kr + (size_t)(b * 8 + hkv) * S_ * HD;
  const u16* Vg = vt + (size_t)(b * 8 + hkv) * HD * S_;

  const int q0w = t * 128 + wave * 32;
  const int nsteps = 2 * (t + 1);

  short8 qf[8];
#pragma unroll
  for (int ki = 0; ki < 8; ++ki)
    qf[ki] = *(const short8*)(Q + (size_t)(q0w + ql) * HD + ki * 16 + lh * 8);

  f32x16 o[4];
#pragma unroll
  for (int dt = 0; dt < 4; ++dt) o[dt] = 0.f;
  float m = -1e30f, l = 0.f;

  auto stage = [&](int buf, int kv0) {
#pragma unroll
    for (int inst = 0; inst < 4; ++inst) {
      int pp2 = wave * 4096 + inst * 1024 + lane * 16;
      int row = pp2 >> 8;
      int colb = (pp2 & 255) ^ ((row & 7) << 4);
      load_lds16(Kg + (((size_t)(kv0 + row)) << 7) + (colb >> 1),
                 &Ks[buf][(wave * 4096 + inst * 1024) >> 1]);
    }
#pragma unroll
    for (int inst = 0; inst < 4; ++inst) {
      int pp2 = wave * 4096 + inst * 1024 + lane * 16;
      int d = pp2 >> 7;
      int colb = (pp2 & 127) ^ ((d & 7) << 4);
      load_lds16(Vg + (size_t)d * S_ + kv0 + (colb >> 1),
                 &Vs[buf][(wave * 4096 + inst * 1024) >> 1]);
    }
  };

  stage(0, 0);
  for (int i = 0; i < nsteps; ++i) {
    const int kv0 = i * 64;
    const u16* kb = Ks[i & 1];
    const u16* vb = Vs[i & 1];
    if (i + 1 < nsteps) {
      stage((i + 1) & 1, kv0 + 64);
      ASM_VMCNT(8);
    } else {
      ASM_VMCNT(0);
    }
    SBAR;

    if (kv0 < q0w + 32) {
      f32x16 sacc[2];
      sacc[0] = 0.f; sacc[1] = 0.f;
      __builtin_amdgcn_s_setprio(1);
#pragma unroll
      for (int ki = 0; ki < 8; ++ki) {
        const int off = ki * 32 + lh * 16;
#pragma unroll
        for (int kvt = 0; kvt < 2; ++kvt) {
          const int row = kvt * 32 + ql;
          short8 kf = *(const short8*)&kb[(row << 7) + ((off ^ ((row & 7) << 4)) >> 1)];
          sacc[kvt] = __builtin_amdgcn_mfma_f32_32x32x16_bf16(kf, qf[ki], sacc[kvt], 0, 0, 0);
        }
      }
      __builtin_amdgcn_s_setprio(0);
      const int q = q0w + ql;
      if (kv0 + 64 > q0w) {
#pragma unroll
        for (int kvt = 0; kvt < 2; ++kvt) {
          const int kvb = kv0 + kvt * 32 + 4 * lh;
#pragma unroll
          for (int reg = 0; reg < 16; ++reg) {
            const int kvr = kvb + (reg & 3) + 8 * (reg >> 2);
            sacc[kvt][reg] = (kvr > q) ? -1e30f : sacc[kvt][reg];
          }
        }
      }
      float mx = sacc[0][0];
#pragma unroll
      for (int kvt = 0; kvt < 2; ++kvt)
#pragma unroll
        for (int reg = 0; reg < 16; ++reg) mx = fmaxf(mx, sacc[kvt][reg]);
      mx = fmaxf(mx, __shfl_xor(mx, 32, 64));
      if (__any(mx > m + RTHR)) {
        float mn = fmaxf(m, mx);
        float sc = exp2f_fast((m - mn) * CEXP);
        l *= sc;
        m = mn;
#pragma unroll
        for (int dt = 0; dt < 4; ++dt)
#pragma unroll
          for (int reg = 0; reg < 16; ++reg) o[dt][reg] *= sc;
      }
      short8 pf[4];
      const float mc = m * CEXP;
      float ps = 0.f;
#pragma unroll
      for (int kvt = 0; kvt < 2; ++kvt) {
        float pv[16];
#pragma unroll
        for (int reg = 0; reg < 16; ++reg) {
          pv[reg] = exp2f_fast(__builtin_fmaf(sacc[kvt][reg], CEXP, -mc));
          ps += pv[reg];
        }
        int A0 = cvtpk(pv[0], pv[1]),  B0 = cvtpk(pv[2], pv[3]);
        int C0 = cvtpk(pv[4], pv[5]),  D0 = cvtpk(pv[6], pv[7]);
        int A1 = cvtpk(pv[8], pv[9]),  B1 = cvtpk(pv[10], pv[11]);
        int C1 = cvtpk(pv[12], pv[13]), D1 = cvtpk(pv[14], pv[15]);
        pl32swap(A0, C0);
        pl32swap(B0, D0);
        pl32swap(A1, C1);
        pl32swap(B1, D1);
        i32x4 w0 = (i32x4){A0, B0, C0, D0};
        i32x4 w1 = (i32x4){A1, B1, C1, D1};
        pf[kvt * 2]     = *(short8*)&w0;
        pf[kvt * 2 + 1] = *(short8*)&w1;
      }
      l += ps;
      __builtin_amdgcn_s_setprio(1);
#pragma unroll
      for (int kc = 0; kc < 4; ++kc) {
        const int off = kc * 32 + lh * 16;
#pragma unroll
        for (int dt = 0; dt < 4; ++dt) {
          const int d = dt * 32 + ql;
          short8 vf = *(const short8*)&vb[(d << 6) + ((off ^ ((d & 7) << 4)) >> 1)];
          o[dt] = __builtin_amdgcn_mfma_f32_32x32x16_bf16(vf, pf[kc], o[dt], 0, 0, 0);
        }
      }
      __builtin_amdgcn_s_setprio(0);
    }
    SBAR;
  }

  l += __shfl_xor(l, 32, 64);
  const float inv = 1.0f / l;
  const size_t rowoff = ((size_t)(b * 2048 + q0w + ql)) * 2048 + h * 128;
#pragma unroll
  for (int dt = 0; dt < 4; ++dt)
#pragma unroll
    for (int g = 0; g < 4; ++g) {
      const int d0 = dt * 32 + 8 * g + 4 * lh;
      int w0 = cvtpk(o[dt][4 * g] * inv, o[dt][4 * g + 1] * inv);
      int w1 = cvtpk(o[dt][4 * g + 2] * inv, o[dt][4 * g + 3] * inv);
      i32x2 pk = (i32x2){w0, w1};
      *(i32x2*)((u16*)ao + rowoff + d0) = pk;
    }
}

extern "C" void kernel_launch(void* const* d_in, const int* in_sizes, int n_in,
                              void* d_out, int out_size, void* d_ws, size_t ws_size,
                              hipStream_t stream) {
  const float* x = (const float*)d_in[0];
  const float* fc = (const float*)d_in[1];
  const float* wq = (const float*)d_in[2];
  const float* wk = (const float*)d_in[3];
  const float* wv = (const float*)d_in[4];
  const float* wo = (const float*)d_in[5];
  const float* qw = (const float*)d_in[6];
  const float* kw = (const float*)d_in[7];
  float* out = (float*)d_out;
  char* ws = (char*)d_ws;

  u16* xb    = (u16*)(ws);                 // [4096][2048] bf16   16 MB
  u16* wqkvb = (u16*)(ws + 16777216);      // [4096][2048] bf16   16 MB
  u16* wob   = (u16*)(ws + 33554432);      // [2048][2048] bf16    8 MB
  u16* qkv   = (u16*)(ws + 41943040);      // [4096][4096] bf16   32 MB
  u16* qrope = (u16*)(ws + 75497472);      // [2][16][2048][128]  16 MB
  u16* krope = (u16*)(ws + 92274688);      // [2][8][2048][128]    8 MB
  u16* vtb   = (u16*)(ws + 100663296);     // [2][8][128][2048]    8 MB
  u16* ao    = (u16*)(ws + 109051904);     // [4096][2048] bf16   16 MB

  cvt_all<<<20480, 256, 0, stream>>>(x, wq, wk, wv, wo, xb, wqkvb, wob);

  gemm256<0><<<256, 512, 0, stream>>>(xb, wqkvb, (void*)qkv, 4096, 4096, 2048, 16);

  rmsnorm_rope<<<24576, 256, 0, stream>>>(qkv, fc, qw, kw, qrope, krope);
  v_transpose<<<512, 256, 0, stream>>>(qkv, vtb);

  attn6<<<512, 256, 0, stream>>>(qrope, krope, vtb, ao);

  gemm_bt2<1><<<512, 256, 0, stream>>>(ao, wob, (void*)out, 4096, 2048, 2048, 16);
}